// Round 8
// baseline (205.834 us; speedup 1.0000x reference)
//
#include <hip/hip_runtime.h>
#include <math.h>

#define NGRAPH 256
#define NPG 256
#define HF 128
#define EPG 4096
#define PSTR 136    // h-pair row stride (shorts): 272B, 16B-aligned, 2-way banks
#define SSTR 264    // Gt row stride (shorts): 528B, 16B-aligned, 2-way banks
#define ASTR 40     // A-tile row stride (shorts): 80B, 16B-aligned, spread banks

typedef __attribute__((ext_vector_type(8))) short bf16x8;
typedef __attribute__((ext_vector_type(4))) float f32x4;

static __device__ __forceinline__ unsigned bcu(float f){ return __builtin_bit_cast(unsigned, f); }
static __device__ __forceinline__ float bcf(unsigned u){ return __builtin_bit_cast(float, u); }
static __device__ __forceinline__ unsigned rtn16(float f){
  unsigned u = bcu(f);
  return (u + 0x7FFFu + ((u >> 16) & 1u)) >> 16;
}

// ---------------- W transpose + split to bf16 hi/lo: Wt[n][k] ----------------
__global__ __launch_bounds__(256) void prep_wt(const float* __restrict__ W1,
                                               const float* __restrict__ W2,
                                               const float* __restrict__ W3,
                                               short* __restrict__ Wt) {
  int idx = blockIdx.x * 256 + threadIdx.x;
  int L = idx >> 14, r = idx & 16383;
  int k = r >> 7, n = r & 127;
  const float* W = (L == 0) ? W1 : (L == 1) ? W2 : W3;
  float w = W[k*128 + n];
  unsigned hi = rtn16(w);
  float lo = w - bcf(hi << 16);
  short* Whi = Wt + (size_t)L * 2 * 16384;
  short* Wlo = Whi + 16384;
  Whi[n*128 + k] = (short)hi;
  Wlo[n*128 + k] = (short)(bcu(lo) >> 16);
}

// sort compare-exchange step (descending key, ascending idx on ties)
#define BSTEP(OK, OI, KKc, Jc) do { \
  bool iLess = ((tid & (Jc)) == 0); \
  bool descR = ((tid & (KKc)) == 0); \
  bool myFirst = (kf > (OK)) || (kf == (OK) && ki < (OI)); \
  bool keep = (iLess == descR) ? myFirst : !myFirst; \
  if (!keep) { kf = (OK); ki = (OI); } \
} while (0)

// ---------------- whole network, one block per graph ----------------
__global__ __launch_bounds__(1024, 4) void fused_net(
    const float* __restrict__ x,
    const int* __restrict__ srcI, const int* __restrict__ dstI,
    const short* __restrict__ WtAll,
    const float* __restrict__ b1, const float* __restrict__ Ws1, const float* __restrict__ bs1,
    const float* __restrict__ b2, const float* __restrict__ Ws2, const float* __restrict__ bs2,
    const float* __restrict__ b3, const float* __restrict__ Ws3, const float* __restrict__ bs3,
    const float* __restrict__ Wl1, const float* __restrict__ bl1,
    const float* __restrict__ Wl2, const float* __restrict__ bl2,
    const float* __restrict__ Wl3, const float* __restrict__ bl3,
    float* __restrict__ out)
{
  // region A (139264B): init-bitmaps -> h-pair -> {Gt pair + slack arrays} -> h'-pair ...
  __shared__ __align__(16) unsigned char regA[139264];
  // region B (20480B): cntA / A-tile / red+scoreA / zr  (time-disjoint)
  __shared__ __align__(16) unsigned char regB[20480];
  __shared__ unsigned mbits[8];   // survivor bitmask (persistent)
  __shared__ unsigned sbits[8];   // nodes having a real self-edge (persistent)

  short* hp0 = (short*)regA;                 // [256][PSTR]
  short* hp1 = hp0 + NPG*PSTR;
  short* Gt0 = (short*)regA;                 // [128][SSTR] (aliases hp)
  short* Gt1 = Gt0 + HF*SSTR;
  float* dinv = (float*)(regA + 135168);     // 256 (Gt-phase slack)
  float* tqv  = dinv + NPG;                  // 256
  float* skey = tqv + NPG;                   // 256
  int*   sidx = (int*)(skey + NPG);          // 256
  short* Atile  = (short*)regB;              // [256][ASTR]
  float* red    = (float*)regB;              // 1024 (post-agg phases)
  float* scoreA = (float*)(regB + 4096);     // 256  (post-agg phases)
  int*   cntA   = (int*)(regB + 5120);       // 256  (layer-start phase)
  float* zr     = (float*)(regB + 5120);     // 256  (MLP)
  unsigned* bm  = (unsigned*)regA;           // 6 bitmaps x 2048 words (init only)

  int tid = threadIdx.x;
  int g = blockIdx.x;
  size_t nbase = (size_t)g * NPG;
  int lane = tid & 63, wid = tid >> 6;
  int rg = wid & 7, cg = wid >> 3;
  int lr = lane & 15, kq = lane >> 4;

  // ---- edges into registers ----
  int nb = g * NPG;
  int ed[4], es[4];
  #pragma unroll
  for (int it = 0; it < 4; ++it) {
    int e = g*EPG + tid + it*1024;
    ed[it] = dstI[e] - nb;
    es[it] = srcI[e] - nb;
  }

  // ---- dedup: 6-level bitmap chain -> exact multiplicity per owned edge ----
  for (int i = tid; i < 12288; i += 1024) bm[i] = 0;
  if (tid < 8) { mbits[tid] = 0xFFFFFFFFu; sbits[tid] = 0u; }
  __syncthreads();
  unsigned ownm[4];
  #pragma unroll
  for (int it = 0; it < 4; ++it) {
    unsigned key = (unsigned)(ed[it]*256 + es[it]);
    unsigned w = key >> 5, b = 1u << (key & 31);
    unsigned o = atomicOr(&bm[w], b);
    bool owner = ((o & b) == 0);
    if (!owner) {
      o = atomicOr(&bm[2048 + w], b);
      if (o & b) { o = atomicOr(&bm[4096 + w], b);
        if (o & b) { o = atomicOr(&bm[6144 + w], b);
          if (o & b) { o = atomicOr(&bm[8192 + w], b);
            if (o & b) atomicOr(&bm[10240 + w], b); } } }
    }
    ownm[it] = owner ? 1u : 0u;
  }
  __syncthreads();
  int epk[4];
  #pragma unroll
  for (int it = 0; it < 4; ++it) {
    unsigned m = 0;
    if (ownm[it]) {
      unsigned key = (unsigned)(ed[it]*256 + es[it]);
      unsigned w = key >> 5, b = 1u << (key & 31);
      m = 1u;
      m += (bm[2048 + w] & b) ? 1u : 0u;
      m += (bm[4096 + w] & b) ? 1u : 0u;
      m += (bm[6144 + w] & b) ? 1u : 0u;
      m += (bm[8192 + w] & b) ? 1u : 0u;
      m += (bm[10240 + w] & b) ? 1u : 0u;
      if (es[it] == ed[it]) atomicOr(&sbits[ed[it] >> 5], 1u << (ed[it] & 31));
    }
    epk[it] = ed[it] | (es[it] << 8) | ((int)m << 16);
  }
  __syncthreads();   // bitmap reads done; regA free for staging

  // ---- stage x into h-pair (bf16 hi/lo) ----
  {
    const float4* X4 = (const float4*)(x + nbase*HF);
    #pragma unroll
    for (int i = 0; i < 8; ++i) {
      int f4 = tid + i*1024;
      int r = f4 >> 5, q = f4 & 31;
      float4 val = X4[f4];
      unsigned rx = rtn16(val.x), ry = rtn16(val.y), rz = rtn16(val.z), rw = rtn16(val.w);
      uint2 ph; ph.x = rx | (ry << 16); ph.y = rz | (rw << 16);
      float lx = val.x - bcf(rx << 16), ly = val.y - bcf(ry << 16);
      float lz = val.z - bcf(rz << 16), lw = val.w - bcf(rw << 16);
      uint2 pl; pl.x = (bcu(lx) >> 16) | (bcu(ly) & 0xFFFF0000u);
      pl.y = (bcu(lz) >> 16) | (bcu(lw) & 0xFFFF0000u);
      *(uint2*)&hp0[r*PSTR + q*4] = ph;
      *(uint2*)&hp1[r*PSTR + q*4] = pl;
    }
  }

  float zmx = 0.f, zmn = 0.f;   // readout accumulators (meaningful for tid<128)

  // ================= 3 GCN+SAGPool layers =================
  #pragma unroll 1
  for (int L = 0; L < 3; ++L) {
    const short* Whi = WtAll + (size_t)L * 2 * 16384;
    const short* Wlo = Whi + 16384;
    const float* bias = (L == 0) ? b1 : (L == 1) ? b2 : b3;
    const float* Wsc  = (L == 0) ? Ws1 : (L == 1) ? Ws2 : Ws3;
    const float* bscp = (L == 0) ? bs1 : (L == 1) ? bs2 : bs3;
    int K = NPG >> (L + 1);          // 128, 64, 32

    __syncthreads();   // B0: h-pair ready; prev-layer regB uses done

    if (tid < NPG) cntA[tid] = (int)((mbits[tid>>5] >> (tid&31)) & 1);  // self-loop if alive
    float bvr[4], wvr[4];
    #pragma unroll
    for (int ct = 0; ct < 4; ++ct) {
      int f = cg*64 + ct*16 + lr;
      bvr[ct] = bias[f];
      wvr[ct] = Wsc[f];
    }
    float bscv = bscp[0];
    __syncthreads();   // B0b: cnt init visible

    // degree atomics (masked, multiplicity-weighted)
    #pragma unroll
    for (int it = 0; it < 4; ++it) {
      int d = epk[it] & 255, s = (epk[it] >> 8) & 255, m = epk[it] >> 16;
      if (m) {
        unsigned as = (mbits[s>>5] >> (s&31)) & 1;
        unsigned ad = (mbits[d>>5] >> (d&31)) & 1;
        if (as & ad) atomicAdd(&cntA[d], m);
      }
    }

    // ---- transform T = h @ W (MFMA, h-pair x W-pair) ----
    f32x4 tacc[2][4] = {};
    #pragma unroll
    for (int kc = 0; kc < 4; ++kc) {
      int k0 = kc*32 + kq*8;
      bf16x8 ah[2], al[2];
      #pragma unroll
      for (int rt = 0; rt < 2; ++rt) {
        int row = rg*32 + rt*16 + lr;
        ah[rt] = *(const bf16x8*)&hp0[row*PSTR + k0];
        al[rt] = *(const bf16x8*)&hp1[row*PSTR + k0];
      }
      #pragma unroll
      for (int ct = 0; ct < 4; ++ct) {
        int n = cg*64 + ct*16 + lr;
        bf16x8 bh = *(const bf16x8*)&Whi[n*HF + k0];
        bf16x8 bl = *(const bf16x8*)&Wlo[n*HF + k0];
        #pragma unroll
        for (int rt = 0; rt < 2; ++rt) {
          tacc[rt][ct] = __builtin_amdgcn_mfma_f32_16x16x32_bf16(ah[rt], bh, tacc[rt][ct], 0, 0, 0);
          tacc[rt][ct] = __builtin_amdgcn_mfma_f32_16x16x32_bf16(al[rt], bh, tacc[rt][ct], 0, 0, 0);
          tacc[rt][ct] = __builtin_amdgcn_mfma_f32_16x16x32_bf16(ah[rt], bl, tacc[rt][ct], 0, 0, 0);
        }
      }
    }
    __syncthreads();   // B1: h reads done; degree atomics complete

    // ---- epilogue: Gt[f][s] = split(dinv[s] * T[s][f]) ; dinv array ----
    {
      unsigned mwrow = mbits[rg];
      #pragma unroll
      for (int rt = 0; rt < 2; ++rt) {
        int row0 = rg*32 + rt*16 + kq*4;
        float dv[4];
        #pragma unroll
        for (int j = 0; j < 4; ++j) {
          int d = row0 + j;
          int c = cntA[d];
          dv[j] = ((mwrow >> (d & 31)) & 1) ? (1.0f/sqrtf((float)c)) : 0.f;
        }
        #pragma unroll
        for (int ct = 0; ct < 4; ++ct) {
          int f = cg*64 + ct*16 + lr;
          #pragma unroll
          for (int j = 0; j < 4; ++j) {
            float val = tacc[rt][ct][j] * dv[j];
            unsigned hi = rtn16(val);
            float lo = val - bcf(hi << 16);
            Gt0[f*SSTR + row0 + j] = (short)hi;
            Gt1[f*SSTR + row0 + j] = (short)(bcu(lo) >> 16);
          }
        }
      }
      if (tid < NPG) {
        int c = cntA[tid];
        dinv[tid] = ((mbits[tid>>5] >> (tid&31)) & 1) ? (1.0f/sqrtf((float)c)) : 0.f;
      }
    }
    __syncthreads();   // B2: Gt + dinv ready; cnt dead

    // ---- zero A-tile ----
    {
      uint4 z; z.x = z.y = z.z = z.w = 0u;
      uint4* A4 = (uint4*)Atile;
      A4[tid] = z;
      if (tid < 256) A4[1024 + tid] = z;
    }
    __syncthreads();   // B2b

    // ---- aggregation: C = A * (Ghi + Glo), streamed 32-source tiles ----
    f32x4 aacc[2][4] = {};
    #pragma unroll 1
    for (int ks = 0; ks < 8; ++ks) {
      // scatter current tile (owner-unique slots; no races within a step)
      #pragma unroll
      for (int it = 0; it < 4; ++it) {
        int d = epk[it] & 255, s = (epk[it] >> 8) & 255, m = epk[it] >> 16;
        if (m && (s >> 5) == ks)
          Atile[d*ASTR + (s & 31)] = (short)rtn16((float)(m + (s == d ? 1 : 0)));
      }
      if ((tid >> 5) == ks && !((sbits[ks] >> (tid & 31)) & 1))
        Atile[tid*ASTR + (tid & 31)] = (short)0x3F80;   // self-loop 1.0
      __syncthreads();   // Ka: tile built
      {
        bf16x8 af[2];
        #pragma unroll
        for (int rt = 0; rt < 2; ++rt)
          af[rt] = *(const bf16x8*)&Atile[(rg*32 + rt*16 + lr)*ASTR + kq*8];
        int k0 = ks*32 + kq*8;
        #pragma unroll
        for (int ct = 0; ct < 4; ++ct) {
          int f = cg*64 + ct*16 + lr;
          bf16x8 gh = *(const bf16x8*)&Gt0[f*SSTR + k0];
          bf16x8 gl = *(const bf16x8*)&Gt1[f*SSTR + k0];
          #pragma unroll
          for (int rt = 0; rt < 2; ++rt) {
            aacc[rt][ct] = __builtin_amdgcn_mfma_f32_16x16x32_bf16(af[rt], gh, aacc[rt][ct], 0, 0, 0);
            aacc[rt][ct] = __builtin_amdgcn_mfma_f32_16x16x32_bf16(af[rt], gl, aacc[rt][ct], 0, 0, 0);
          }
        }
      }
      __syncthreads();   // Kb: tile consumed
      if (ks < 7) {
        // unscatter (same owners -> race-free)
        #pragma unroll
        for (int it = 0; it < 4; ++it) {
          int d = epk[it] & 255, s = (epk[it] >> 8) & 255, m = epk[it] >> 16;
          if (m && (s >> 5) == ks) Atile[d*ASTR + (s & 31)] = 0;
        }
        if ((tid >> 5) == ks && !((sbits[ks] >> (tid & 31)) & 1))
          Atile[tid*ASTR + (tid & 31)] = 0;
        __syncthreads();   // Kc: tile cleared
      }
    }

    // ---- relu + bias + fused score partial (registers + shfl) ----
    f32x4 hreg[2][4];
    #pragma unroll
    for (int rt = 0; rt < 2; ++rt) {
      int row0 = rg*32 + rt*16 + kq*4;
      float dv[4], part[4];
      #pragma unroll
      for (int j = 0; j < 4; ++j) { dv[j] = dinv[row0 + j]; part[j] = 0.f; }
      #pragma unroll
      for (int ct = 0; ct < 4; ++ct) {
        #pragma unroll
        for (int j = 0; j < 4; ++j) {
          float h = fmaxf(fmaf(dv[j], aacc[rt][ct][j], bvr[ct]), 0.f);
          hreg[rt][ct][j] = h;
          part[j] += h * wvr[ct];
        }
      }
      #pragma unroll
      for (int j = 0; j < 4; ++j) {
        float p = part[j];
        p += __shfl_xor(p, 1); p += __shfl_xor(p, 2);
        p += __shfl_xor(p, 4); p += __shfl_xor(p, 8);
        if (lr == 0) red[cg*256 + row0 + j] = p;
      }
    }
    __syncthreads();   // B3
    if (tid < NPG) {
      float t = (red[tid] + red[256 + tid]) * dinv[tid];   // tq (0 for dead)
      tqv[tid] = t;
      scoreA[tid] = t;                                     // self term
    }
    __syncthreads();   // B4
    #pragma unroll
    for (int it = 0; it < 4; ++it) {
      int d = epk[it] & 255, s = (epk[it] >> 8) & 255, m = epk[it] >> 16;
      if (m) atomicAdd(&scoreA[d], (float)m * tqv[s]);     // dead s -> tq 0
    }
    __syncthreads();   // B5
    float sc = 0.f; bool aliveMe = false;
    if (tid < NPG) {
      sc = dinv[tid]*scoreA[tid] + bscv;
      scoreA[tid] = sc;
      aliveMe = ((mbits[tid>>5] >> (tid&31)) & 1) != 0;
    }

    // ---- register bitonic top-K (4 waves), desc score / asc idx ----
    float kf = -INFINITY; int ki = tid;
    if (tid < NPG) {
      kf = aliveMe ? sc : -INFINITY;
      for (int kk = 2; kk <= 64; kk <<= 1)
        for (int j = kk >> 1; j > 0; j >>= 1) {
          float ok = __shfl_xor(kf, j);
          int   oi = __shfl_xor(ki, j);
          BSTEP(ok, oi, kk, j);
        }
    }
    if (tid < NPG) { skey[tid] = kf; sidx[tid] = ki; }
    else if (tid < NPG + 8) mbits[tid - NPG] = 0u;   // clear mask mid-sort
    __syncthreads();
    if (tid < NPG) {
      int l = tid ^ 64; float ok = skey[l]; int oi = sidx[l];
      BSTEP(ok, oi, 128, 64);
      for (int j = 32; j > 0; j >>= 1) {
        float sk = __shfl_xor(kf, j); int si = __shfl_xor(ki, j);
        BSTEP(sk, si, 128, j);
      }
    }
    __syncthreads();
    if (tid < NPG) { skey[tid] = kf; sidx[tid] = ki; }
    __syncthreads();
    if (tid < NPG) {
      int l = tid ^ 128; float ok = skey[l]; int oi = sidx[l];
      BSTEP(ok, oi, 256, 128);
    }
    __syncthreads();
    if (tid < NPG) { skey[tid] = kf; sidx[tid] = ki; }
    __syncthreads();
    if (tid < NPG) {
      int l = tid ^ 64; float ok = skey[l]; int oi = sidx[l];
      BSTEP(ok, oi, 256, 64);
      for (int j = 32; j > 0; j >>= 1) {
        float sk = __shfl_xor(kf, j); int si = __shfl_xor(ki, j);
        BSTEP(sk, si, 256, j);
      }
    }
    if (tid < K) atomicOr(&mbits[ki >> 5], 1u << (ki & 31));
    __syncthreads();   // B7: new mask ready
    if (tid < NPG) {
      unsigned a2 = (mbits[tid>>5] >> (tid&31)) & 1;
      scoreA[tid] = a2 ? tanhf(scoreA[tid]) : 0.f;   // tanh x mask
    }
    __syncthreads();   // B8

    // ---- scale + pack (L<2) + in-register readout partials ----
    {
      unsigned mwNew = mbits[rg];
      float mx[4], sm[4];
      #pragma unroll
      for (int ct = 0; ct < 4; ++ct) { mx[ct] = -INFINITY; sm[ct] = 0.f; }
      #pragma unroll
      for (int rt = 0; rt < 2; ++rt) {
        int row0 = rg*32 + rt*16 + kq*4;
        float ts[4];
        #pragma unroll
        for (int j = 0; j < 4; ++j) ts[j] = scoreA[row0 + j];
        #pragma unroll
        for (int ct = 0; ct < 4; ++ct) {
          int f = cg*64 + ct*16 + lr;
          #pragma unroll
          for (int j = 0; j < 4; ++j) {
            float h2 = hreg[rt][ct][j] * ts[j];
            bool alive = (mwNew >> ((row0 + j) & 31)) & 1;
            if (alive) { mx[ct] = fmaxf(mx[ct], h2); sm[ct] += h2; }
            if (L < 2) {
              unsigned hi = rtn16(h2);
              float lo = h2 - bcf(hi << 16);
              hp0[(row0 + j)*PSTR + f] = (short)hi;
              hp1[(row0 + j)*PSTR + f] = (short)(bcu(lo) >> 16);
            }
          }
        }
      }
      // combine across the 4 kq groups
      #pragma unroll
      for (int ct = 0; ct < 4; ++ct) {
        mx[ct] = fmaxf(mx[ct], __shfl_xor(mx[ct], 16));
        mx[ct] = fmaxf(mx[ct], __shfl_xor(mx[ct], 32));
        sm[ct] += __shfl_xor(sm[ct], 16);
        sm[ct] += __shfl_xor(sm[ct], 32);
      }
      __syncthreads();   // red free (B3 partials consumed)
      if (kq == 0) {
        #pragma unroll
        for (int ct = 0; ct < 4; ++ct) red[rg*128 + cg*64 + ct*16 + lr] = mx[ct];
      }
      __syncthreads();
      if (tid < HF) {
        float m = red[tid];
        #pragma unroll
        for (int q = 1; q < 8; ++q) m = fmaxf(m, red[q*128 + tid]);
        zmx += m;
      }
      __syncthreads();
      if (kq == 0) {
        #pragma unroll
        for (int ct = 0; ct < 4; ++ct) red[rg*128 + cg*64 + ct*16 + lr] = sm[ct];
      }
      __syncthreads();
      if (tid < HF) {
        float s = red[tid];
        #pragma unroll
        for (int q = 1; q < 8; ++q) s += red[q*128 + tid];
        zmn += s / (float)K;
      }
    }
  }

  __syncthreads();
  if (tid < HF) { zr[tid] = zmx; zr[HF + tid] = zmn; }
  __syncthreads();

  // ---- MLP head + log_softmax ----
  {
    int o = tid & 127, kg = tid >> 7;
    float p = 0.f;
    int k0 = kg*32;
    for (int k = k0; k < k0+32; ++k) p += zr[k]*Wl1[k*HF + o];
    red[kg*HF + o] = p;
    __syncthreads();
    if (tid < HF) {
      float a = bl1[tid];
      #pragma unroll
      for (int q = 0; q < 8; ++q) a += red[q*HF + tid];
      scoreA[tid] = fmaxf(a, 0.f);       // h1
    }
    __syncthreads();
    if (tid < 512) {
      int o2 = tid & 63, kg2 = tid >> 6;
      float p2 = 0.f;
      int k0b = kg2*16;
      for (int k = k0b; k < k0b+16; ++k) p2 += scoreA[k]*Wl2[k*64 + o2];
      red[kg2*64 + o2] = p2;
    }
    __syncthreads();
    if (tid < 64) {
      float a = bl2[tid];
      #pragma unroll
      for (int q = 0; q < 8; ++q) a += red[q*64 + tid];
      scoreA[128 + tid] = fmaxf(a, 0.f); // h2
    }
    __syncthreads();
    if (tid < 10) {
      float a = bl3[tid];
      for (int k = 0; k < 64; ++k) a += scoreA[128 + k]*Wl3[k*10 + tid];
      scoreA[192 + tid] = fmaxf(a, 0.f); // logits
    }
    __syncthreads();
    if (tid == 0) {
      float m = scoreA[192];
      for (int i = 1; i < 10; ++i) m = fmaxf(m, scoreA[192 + i]);
      float s = 0.f;
      for (int i = 0; i < 10; ++i) s += expf(scoreA[192 + i] - m);
      scoreA[208] = m; scoreA[209] = logf(s);
    }
    __syncthreads();
    if (tid < 10) out[(size_t)g*10 + tid] = scoreA[192 + tid] - scoreA[208] - scoreA[209];
  }
}

extern "C" void kernel_launch(void* const* d_in, const int* in_sizes, int n_in,
                              void* d_out, int out_size, void* d_ws, size_t ws_size,
                              hipStream_t stream) {
  const float* x   = (const float*)d_in[0];
  const int*  srcI = (const int*)d_in[1];
  const int*  dstI = (const int*)d_in[2];
  const float* W1  = (const float*)d_in[3];
  const float* b1  = (const float*)d_in[4];
  const float* W2  = (const float*)d_in[5];
  const float* b2  = (const float*)d_in[6];
  const float* W3  = (const float*)d_in[7];
  const float* b3  = (const float*)d_in[8];
  const float* Ws1 = (const float*)d_in[9];
  const float* bs1 = (const float*)d_in[10];
  const float* Ws2 = (const float*)d_in[11];
  const float* bs2 = (const float*)d_in[12];
  const float* Ws3 = (const float*)d_in[13];
  const float* bs3 = (const float*)d_in[14];
  const float* Wl1 = (const float*)d_in[15];
  const float* bl1 = (const float*)d_in[16];
  const float* Wl2 = (const float*)d_in[17];
  const float* bl2 = (const float*)d_in[18];
  const float* Wl3 = (const float*)d_in[19];
  const float* bl3 = (const float*)d_in[20];
  float* out = (float*)d_out;

  short* WtAll = (short*)d_ws;   // 3 * 2 * 16384 shorts = 192 KB

  prep_wt<<<192, 256, 0, stream>>>(W1, W2, W3, WtAll);
  fused_net<<<NGRAPH, 1024, 0, stream>>>(x, srcI, dstI, WtAll,
                                         b1, Ws1, bs1, b2, Ws2, bs2, b3, Ws3, bs3,
                                         Wl1, bl1, Wl2, bl2, Wl3, bl3, out);
}

// Round 9
// 133.325 us; speedup vs baseline: 1.5439x; 1.5439x over previous
//
#include <hip/hip_runtime.h>
#include <math.h>

#define NGRAPH 256
#define NPG 256
#define HF 128
#define EPG 4096      // real edges per graph
#define EPG2 4352     // max CSR slots incl one self-edge per node
#define FSTR 132      // f32 row stride in tbufF (aliases hpair)
#define PSTR 136      // short row stride in hpair

typedef __attribute__((ext_vector_type(8))) short bf16x8;
typedef __attribute__((ext_vector_type(4))) float f32x4;

static __device__ __forceinline__ unsigned bcu(float f){ return __builtin_bit_cast(unsigned, f); }
static __device__ __forceinline__ float bcf(unsigned u){ return __builtin_bit_cast(float, u); }
static __device__ __forceinline__ unsigned rtn16(float f){
  unsigned u = bcu(f);
  return (u + 0x7FFFu + ((u >> 16) & 1u)) >> 16;
}

// ---------------- W transpose + split to bf16 hi/lo: Wt[n][k] ----------------
__global__ __launch_bounds__(256) void prep_wt(const float* __restrict__ W1,
                                               const float* __restrict__ W2,
                                               const float* __restrict__ W3,
                                               short* __restrict__ Wt) {
  int idx = blockIdx.x * 256 + threadIdx.x;
  int L = idx >> 14, r = idx & 16383;
  int k = r >> 7, n = r & 127;
  const float* W = (L == 0) ? W1 : (L == 1) ? W2 : W3;
  float w = W[k*128 + n];
  unsigned hi = rtn16(w);
  float lo = w - bcf(hi << 16);
  short* Whi = Wt + (size_t)L * 2 * 16384;
  short* Wlo = Whi + 16384;
  Whi[n*128 + k] = (short)hi;
  Wlo[n*128 + k] = (short)(bcu(lo) >> 16);
}

// sort compare-exchange step (descending key, ascending idx on ties)
#define BSTEP(OK, OI, KKc, Jc) do { \
  bool iLess = ((tid & (Jc)) == 0); \
  bool descR = ((tid & (KKc)) == 0); \
  bool myFirst = (kf > (OK)) || (kf == (OK) && ki < (OI)); \
  bool keep = (iLess == descR) ? myFirst : !myFirst; \
  if (!keep) { kf = (OK); ki = (OI); } \
} while (0)

// single-wave exclusive scan of cntA -> rloc + curA; rloc[NPG] = total
#define WAVE0_SCAN() do { \
  if (wid == 0) { \
    int b4 = lane*4; \
    int c0=cntA[b4+0], c1=cntA[b4+1], c2=cntA[b4+2], c3=cntA[b4+3]; \
    int tot = c0+c1+c2+c3; \
    int run = tot; \
    _Pragma("unroll") \
    for (int off=1; off<64; off<<=1) { \
      int u = __shfl_up(run, off); \
      run += (lane >= off) ? u : 0; \
    } \
    int st = run - tot; \
    rloc[b4+0]=(unsigned short)st; \
    rloc[b4+1]=(unsigned short)(st+c0); \
    rloc[b4+2]=(unsigned short)(st+c0+c1); \
    rloc[b4+3]=(unsigned short)(st+c0+c1+c2); \
    curA[b4+0]=st; curA[b4+1]=st+c0; curA[b4+2]=st+c0+c1; curA[b4+3]=st+c0+c1+c2; \
    if (lane == 63) rloc[NPG] = (unsigned short)run; \
  } \
} while (0)

// ---------------- whole network, one block per graph ----------------
__global__ __launch_bounds__(1024) __attribute__((amdgpu_waves_per_eu(4, 4)))
void fused_net(
    const float* __restrict__ x,
    const int* __restrict__ srcI, const int* __restrict__ dstI,
    const short* __restrict__ WtAll,
    const float* __restrict__ b1, const float* __restrict__ Ws1, const float* __restrict__ bs1,
    const float* __restrict__ b2, const float* __restrict__ Ws2, const float* __restrict__ bs2,
    const float* __restrict__ b3, const float* __restrict__ Ws3, const float* __restrict__ bs3,
    const float* __restrict__ Wl1, const float* __restrict__ bl1,
    const float* __restrict__ Wl2, const float* __restrict__ bl2,
    const float* __restrict__ Wl3, const float* __restrict__ bl3,
    float* __restrict__ out)
{
  __shared__ __align__(16) short hpair[2][NPG*PSTR];   // 139264 B; aliased by tbufF
  __shared__ unsigned char colS[EPG2 + 8];             // compacted CSR col, by dst, incl self
  __shared__ unsigned short rloc[NPG+2];
  __shared__ unsigned mbits[8];                        // survivor bitmask
  __shared__ float dinv[NPG];
  __shared__ __align__(16) float bvec[HF];
  __shared__ __align__(16) float wsv[HF];
  __shared__ float score[NPG];
  __shared__ float tscale[NPG];                        // tq scratch / tanh scale
  __shared__ float nmf[NPG];
  __shared__ float skey[NPG];
  __shared__ int   sidx[NPG];
  __shared__ __align__(16) float red[1024];            // partials / readout / MLP scratch
  __shared__ float zacc[2*HF];

  float* tbufF = (float*)&hpair[0][0];                 // [node][FSTR] f32 (G rows), alias
  short* hp0 = &hpair[0][0];
  short* hp1 = &hpair[1][0];
  int* cntA = (int*)skey;                              // CSR-build aliases (sort idle)
  int* curA = sidx;

  int tid = threadIdx.x;
  int g = blockIdx.x;
  size_t nbase = (size_t)g * NPG;
  int lane = tid & 63, wid = tid >> 6;
  int v = tid >> 2, fq = tid & 3, cb = fq * 4;

  // ---- stage x into bf16 hi/lo pair ----
  const float4* X4 = (const float4*)(x + nbase*HF);
  #pragma unroll
  for (int i = 0; i < 8; ++i) {
    int f4 = tid + i*1024;
    int r = f4 >> 5, kq = f4 & 31;
    float4 val = X4[f4];
    unsigned rx = rtn16(val.x), ry = rtn16(val.y), rz = rtn16(val.z), rw = rtn16(val.w);
    uint2 ph; ph.x = rx | (ry << 16); ph.y = rz | (rw << 16);
    float lx = val.x - bcf(rx << 16), ly = val.y - bcf(ry << 16);
    float lz = val.z - bcf(rz << 16), lw = val.w - bcf(rw << 16);
    uint2 pl; pl.x = (bcu(lx) >> 16) | (bcu(ly) & 0xFFFF0000u);
    pl.y = (bcu(lz) >> 16) | (bcu(lw) & 0xFFFF0000u);
    *(uint2*)&hp0[r*PSTR + kq*4] = ph;
    *(uint2*)&hp1[r*PSTR + kq*4] = pl;
  }

  // ---- edges into registers (kept all layers) ----
  int nb = g * NPG;
  int dloc[4], sloc[4];
  #pragma unroll
  for (int it = 0; it < 4; ++it) {
    int e = g*EPG + tid + it*1024;
    dloc[it] = dstI[e] - nb;
    sloc[it] = srcI[e] - nb;
  }

  // ---- initial CSR build (all alive, +1 self slot per node) ----
  if (tid < NPG) cntA[tid] = 1;
  if (tid < 8) mbits[tid] = 0xFFFFFFFFu;
  __syncthreads();
  #pragma unroll
  for (int it = 0; it < 4; ++it) atomicAdd(&cntA[dloc[it]], 1);
  __syncthreads();
  WAVE0_SCAN();
  __syncthreads();
  #pragma unroll
  for (int it = 0; it < 4; ++it) {
    int slot = atomicAdd(&curA[dloc[it]], 1);
    colS[slot] = (unsigned char)sloc[it];
  }
  if (tid < NPG) colS[rloc[tid+1] - 1] = (unsigned char)tid;  // self in last slot

  // ---- 3 GCN+SAGPool layers ----
  #pragma unroll 1
  for (int L = 0; L < 3; ++L) {
    const short* Whi = WtAll + (size_t)L * 2 * 16384;
    const short* Wlo = Whi + 16384;
    const float* bias = (L == 0) ? b1 : (L == 1) ? b2 : b3;
    const float* Wsc  = (L == 0) ? Ws1 : (L == 1) ? Ws2 : Ws3;
    const float* bscp = (L == 0) ? bs1 : (L == 1) ? bs2 : bs3;
    int K = NPG >> (L + 1);          // 128, 64, 32

    __syncthreads();   // B0: pack + CSR (re)build complete

    // ---- params + dinv (compacted row length IS the degree incl self) ----
    if (tid < HF) { bvec[tid] = bias[tid]; wsv[tid] = Wsc[tid]; }
    if (tid < NPG) {
      int c = (int)rloc[tid+1] - (int)rloc[tid];
      bool alive = (mbits[tid>>5] >> (tid&31)) & 1;
      dinv[tid] = alive ? (1.0f / sqrtf((float)c)) : 0.0f;
    }

    // ---- transform: G = dinv * (h @ W)  (MFMA on resident bf16 pair, in place) ----
    {
      int rg = wid & 7, cg = wid >> 3;
      int lr = lane & 15, lk8 = (lane >> 4) * 8;
      f32x4 tacc[2][4] = {};
      #pragma unroll
      for (int kc = 0; kc < 4; ++kc) {
        int k0 = kc*32 + lk8;
        bf16x8 ah[2], al[2];
        #pragma unroll
        for (int rt = 0; rt < 2; ++rt) {
          int row = rg*32 + rt*16 + lr;
          ah[rt] = *(const bf16x8*)&hp0[row*PSTR + k0];
          al[rt] = *(const bf16x8*)&hp1[row*PSTR + k0];
        }
        #pragma unroll
        for (int ct = 0; ct < 4; ++ct) {
          int n = cg*64 + ct*16 + lr;
          bf16x8 bh = *(const bf16x8*)&Whi[n*HF + k0];
          bf16x8 bl = *(const bf16x8*)&Wlo[n*HF + k0];
          #pragma unroll
          for (int rt = 0; rt < 2; ++rt) {
            tacc[rt][ct] = __builtin_amdgcn_mfma_f32_16x16x32_bf16(ah[rt], bh, tacc[rt][ct], 0, 0, 0);
            tacc[rt][ct] = __builtin_amdgcn_mfma_f32_16x16x32_bf16(al[rt], bh, tacc[rt][ct], 0, 0, 0);
            tacc[rt][ct] = __builtin_amdgcn_mfma_f32_16x16x32_bf16(ah[rt], bl, tacc[rt][ct], 0, 0, 0);
          }
        }
      }
      __syncthreads();   // B1: all pair reads done (dinv also complete)
      #pragma unroll
      for (int rt = 0; rt < 2; ++rt) {
        int row0 = rg*32 + rt*16 + (lane >> 4)*4;
        float d0 = dinv[row0+0], d1 = dinv[row0+1], d2 = dinv[row0+2], d3 = dinv[row0+3];
        #pragma unroll
        for (int ct = 0; ct < 4; ++ct) {
          int c = cg*64 + ct*16 + (lane & 15);
          tbufF[(row0+0)*FSTR + c] = tacc[rt][ct][0] * d0;
          tbufF[(row0+1)*FSTR + c] = tacc[rt][ct][1] * d1;
          tbufF[(row0+2)*FSTR + c] = tacc[rt][ct][2] * d2;
          tbufF[(row0+3)*FSTR + c] = tacc[rt][ct][3] * d3;
        }
      }
    }
    __syncthreads();   // B2: G ready

    // ---- aggregation: plain sum of G rows over compacted edges (incl self) ----
    float4 hv[8];
    {
      float4 acc[8] = {};
      int e0 = rloc[v], e1 = rloc[v+1];
      int e = e0;
      for (; e + 1 < e1; e += 2) {
        int s0 = colS[e], s1 = colS[e+1];
        const float* g0 = &tbufF[s0*FSTR + cb];
        const float* g1 = &tbufF[s1*FSTR + cb];
        #pragma unroll
        for (int i = 0; i < 8; ++i) {
          float4 t0 = *(const float4*)&g0[i*16];
          float4 t1 = *(const float4*)&g1[i*16];
          acc[i].x += t0.x; acc[i].y += t0.y; acc[i].z += t0.z; acc[i].w += t0.w;
          acc[i].x += t1.x; acc[i].y += t1.y; acc[i].z += t1.z; acc[i].w += t1.w;
        }
      }
      if (e < e1) {
        const float* g0 = &tbufF[(int)colS[e]*FSTR + cb];
        #pragma unroll
        for (int i = 0; i < 8; ++i) {
          float4 t0 = *(const float4*)&g0[i*16];
          acc[i].x += t0.x; acc[i].y += t0.y; acc[i].z += t0.z; acc[i].w += t0.w;
        }
      }
      float dv = dinv[v];
      float p = 0.f;
      #pragma unroll
      for (int i = 0; i < 8; ++i) {
        int ci = i*16 + cb;
        float4 bv = *(const float4*)&bvec[ci];
        float4 wv = *(const float4*)&wsv[ci];
        float4 a;
        a.x = fmaxf(fmaf(dv, acc[i].x, bv.x), 0.f);
        a.y = fmaxf(fmaf(dv, acc[i].y, bv.y), 0.f);
        a.z = fmaxf(fmaf(dv, acc[i].z, bv.z), 0.f);
        a.w = fmaxf(fmaf(dv, acc[i].w, bv.w), 0.f);
        hv[i] = a;
        p += a.x*wv.x + a.y*wv.y + a.z*wv.z + a.w*wv.w;
      }
      red[tid] = p;
    }
    __syncthreads();   // B3: score partials ready, G reads done
    if (tid < NPG) {
      float4 q = *(const float4*)&red[tid*4];
      tscale[tid] = ((q.x + q.y) + (q.z + q.w)) * dinv[tid];   // tq = (h.Ws)*dinv
      nmf[tid] = 0.f;
    }
    __syncthreads();   // B4
    if (tid < NPG) {
      int e0 = rloc[tid], e1 = rloc[tid+1];
      float sa = 0.f;
      for (int e = e0; e < e1; ++e) sa += tscale[colS[e]];
      score[tid] = dinv[tid] * sa + bscp[0];
    }
    __syncthreads();   // B5: scores ready

    // ---- register bitonic top-K (4 waves), desc score / asc idx ----
    float kf = -INFINITY; int ki = tid;
    if (tid < NPG) {
      kf = (dinv[tid] > 0.f) ? score[tid] : -INFINITY;
      for (int kk = 2; kk <= 64; kk <<= 1)
        for (int j = kk >> 1; j > 0; j >>= 1) {
          float ok = __shfl_xor(kf, j);
          int   oi = __shfl_xor(ki, j);
          BSTEP(ok, oi, kk, j);
        }
    }
    if (tid < NPG) { skey[tid] = kf; sidx[tid] = ki; }
    else if (tid < NPG + 8) mbits[tid - NPG] = 0u;     // clear mask mid-sort (idle waves)
    __syncthreads();
    if (tid < NPG) {
      int l = tid ^ 64; float ok = skey[l]; int oi = sidx[l];
      BSTEP(ok, oi, 128, 64);
      for (int j = 32; j > 0; j >>= 1) {
        float sk = __shfl_xor(kf, j); int si = __shfl_xor(ki, j);
        BSTEP(sk, si, 128, j);
      }
    }
    __syncthreads();
    if (tid < NPG) { skey[tid] = kf; sidx[tid] = ki; }
    __syncthreads();
    if (tid < NPG) {
      int l = tid ^ 128; float ok = skey[l]; int oi = sidx[l];
      BSTEP(ok, oi, 256, 128);
    }
    __syncthreads();
    if (tid < NPG) { skey[tid] = kf; sidx[tid] = ki; }
    __syncthreads();
    if (tid < NPG) {
      int l = tid ^ 64; float ok = skey[l]; int oi = sidx[l];
      BSTEP(ok, oi, 256, 64);
      for (int j = 32; j > 0; j >>= 1) {
        float sk = __shfl_xor(kf, j); int si = __shfl_xor(ki, j);
        BSTEP(sk, si, 256, j);
      }
    }
    if (tid < K) { nmf[ki] = 1.0f; atomicOr(&mbits[ki>>5], 1u << (ki&31)); }
    __syncthreads();
    if (tid < NPG) tscale[tid] = tanhf(score[tid]) * nmf[tid];
    __syncthreads();

    // ---- scale (regs) + write f32 for readout ----
    {
      float ts = tscale[v];
      #pragma unroll
      for (int i = 0; i < 8; ++i) {
        hv[i].x *= ts; hv[i].y *= ts; hv[i].z *= ts; hv[i].w *= ts;
        *(float4*)&tbufF[v*FSTR + i*16 + cb] = hv[i];
      }
    }
    __syncthreads();

    // ---- readout: max & mean over selected nodes -> zacc ----
    {
      int f = tid & 127, vg = tid >> 7;
      float mx = -INFINITY, sm = 0.f;
      for (int vr = 0; vr < 32; ++vr) {
        int vv = vg*32 + vr;
        float val = tbufF[vv*FSTR + f];
        if (nmf[vv] > 0.f) { mx = fmaxf(mx, val); sm += val; }
      }
      red[vg*HF + f] = mx;
      __syncthreads();
      if (tid < HF) {
        float zm = red[tid];
        #pragma unroll
        for (int q = 1; q < 8; ++q) zm = fmaxf(zm, red[q*HF + tid]);
        if (L == 0) zacc[tid] = zm; else zacc[tid] += zm;
      }
      __syncthreads();
      red[vg*HF + f] = sm;
      __syncthreads();
      if (tid < HF) {
        float zs = red[tid];
        #pragma unroll
        for (int q = 1; q < 8; ++q) zs += red[q*HF + tid];
        float mn = zs / (float)K;
        if (L == 0) zacc[HF + tid] = mn; else zacc[HF + tid] += mn;
      }
      __syncthreads();   // all tbufF/red reads done
    }

    if (L < 2) {
      // ---- pack scaled h into bf16 pair for next layer ----
      #pragma unroll
      for (int i = 0; i < 8; ++i) {
        int ci = i*16 + cb;
        float4 val = hv[i];
        unsigned rx = rtn16(val.x), ry = rtn16(val.y), rz = rtn16(val.z), rw = rtn16(val.w);
        uint2 ph; ph.x = rx | (ry << 16); ph.y = rz | (rw << 16);
        float lx = val.x - bcf(rx << 16), ly = val.y - bcf(ry << 16);
        float lz = val.z - bcf(rz << 16), lw = val.w - bcf(rw << 16);
        uint2 pl; pl.x = (bcu(lx) >> 16) | (bcu(ly) & 0xFFFF0000u);
        pl.y = (bcu(lz) >> 16) | (bcu(lw) & 0xFFFF0000u);
        *(uint2*)&hp0[v*PSTR + ci] = ph;
        *(uint2*)&hp1[v*PSTR + ci] = pl;
      }

      // ---- rebuild compacted CSR for the new mask (both endpoints alive) ----
      bool keep[4];
      #pragma unroll
      for (int it = 0; it < 4; ++it) {
        keep[it] = (((mbits[dloc[it]>>5] >> (dloc[it]&31)) & 1) &
                    ((mbits[sloc[it]>>5] >> (sloc[it]&31)) & 1)) != 0;
      }
      bool aliveMe = false;
      if (tid < NPG) aliveMe = (mbits[tid>>5] >> (tid&31)) & 1;
      __syncthreads();               // mbits reads done; cntA/curA (skey/sidx) free
      if (tid < NPG) cntA[tid] = aliveMe ? 1 : 0;
      __syncthreads();
      #pragma unroll
      for (int it = 0; it < 4; ++it)
        if (keep[it]) atomicAdd(&cntA[dloc[it]], 1);
      __syncthreads();
      WAVE0_SCAN();
      __syncthreads();
      #pragma unroll
      for (int it = 0; it < 4; ++it) {
        if (keep[it]) {
          int slot = atomicAdd(&curA[dloc[it]], 1);
          colS[slot] = (unsigned char)sloc[it];
        }
      }
      if (tid < NPG && aliveMe) colS[rloc[tid+1] - 1] = (unsigned char)tid;
      // next-layer B0 covers completion
    }
  }

  __syncthreads();

  // ---- MLP head + log_softmax ----
  {
    int o = tid & 127, kg = tid >> 7;
    float p = 0.f;
    int k0 = kg*32;
    for (int k = k0; k < k0+32; ++k) p += zacc[k]*Wl1[k*HF + o];
    red[kg*HF + o] = p;
    __syncthreads();
    if (tid < HF) {
      float a = bl1[tid];
      #pragma unroll
      for (int q = 0; q < 8; ++q) a += red[q*HF + tid];
      score[tid] = fmaxf(a, 0.f);       // h1
    }
    __syncthreads();
    if (tid < 512) {
      int o2 = tid & 63, kg2 = tid >> 6;
      float p2 = 0.f;
      int k0b = kg2*16;
      for (int k = k0b; k < k0b+16; ++k) p2 += score[k]*Wl2[k*64 + o2];
      red[kg2*64 + o2] = p2;
    }
    __syncthreads();
    if (tid < 64) {
      float a = bl2[tid];
      #pragma unroll
      for (int q = 0; q < 8; ++q) a += red[q*64 + tid];
      tscale[tid] = fmaxf(a, 0.f);      // h2
    }
    __syncthreads();
    if (tid < 10) {
      float a = bl3[tid];
      for (int k = 0; k < 64; ++k) a += tscale[k]*Wl3[k*10 + tid];
      nmf[tid] = fmaxf(a, 0.f);         // logits
    }
    __syncthreads();
    if (tid == 0) {
      float m = nmf[0];
      for (int i = 1; i < 10; ++i) m = fmaxf(m, nmf[i]);
      float s = 0.f;
      for (int i = 0; i < 10; ++i) s += expf(nmf[i] - m);
      red[0] = m; red[1] = logf(s);
    }
    __syncthreads();
    if (tid < 10) out[(size_t)g*10 + tid] = nmf[tid] - red[0] - red[1];
  }
}

extern "C" void kernel_launch(void* const* d_in, const int* in_sizes, int n_in,
                              void* d_out, int out_size, void* d_ws, size_t ws_size,
                              hipStream_t stream) {
  const float* x   = (const float*)d_in[0];
  const int*  srcI = (const int*)d_in[1];
  const int*  dstI = (const int*)d_in[2];
  const float* W1  = (const float*)d_in[3];
  const float* b1  = (const float*)d_in[4];
  const float* W2  = (const float*)d_in[5];
  const float* b2  = (const float*)d_in[6];
  const float* W3  = (const float*)d_in[7];
  const float* b3  = (const float*)d_in[8];
  const float* Ws1 = (const float*)d_in[9];
  const float* bs1 = (const float*)d_in[10];
  const float* Ws2 = (const float*)d_in[11];
  const float* bs2 = (const float*)d_in[12];
  const float* Ws3 = (const float*)d_in[13];
  const float* bs3 = (const float*)d_in[14];
  const float* Wl1 = (const float*)d_in[15];
  const float* bl1 = (const float*)d_in[16];
  const float* Wl2 = (const float*)d_in[17];
  const float* bl2 = (const float*)d_in[18];
  const float* Wl3 = (const float*)d_in[19];
  const float* bl3 = (const float*)d_in[20];
  float* out = (float*)d_out;

  short* WtAll = (short*)d_ws;   // 3 * 2 * 16384 shorts = 192 KB

  prep_wt<<<192, 256, 0, stream>>>(W1, W2, W3, WtAll);
  fused_net<<<NGRAPH, 1024, 0, stream>>>(x, srcI, dstI, WtAll,
                                         b1, Ws1, bs1, b2, Ws2, bs2, b3, Ws3, bs3,
                                         Wl1, bl1, Wl2, bl2, Wl3, bl3, out);
}

// Round 10
// 133.248 us; speedup vs baseline: 1.5447x; 1.0006x over previous
//
#include <hip/hip_runtime.h>
#include <math.h>

#define NGRAPH 256
#define NPG 256
#define HF 128
#define EPG 4096      // real edges per graph
#define EPG2 4352     // max CSR slots incl one self-edge per node
#define FSTR 132      // f32 row stride in tbufF (aliases hpair)
#define PSTR 136      // short row stride in hpair

typedef __attribute__((ext_vector_type(8))) short bf16x8;
typedef __attribute__((ext_vector_type(4))) float f32x4;

static __device__ __forceinline__ unsigned bcu(float f){ return __builtin_bit_cast(unsigned, f); }
static __device__ __forceinline__ float bcf(unsigned u){ return __builtin_bit_cast(float, u); }
static __device__ __forceinline__ unsigned rtn16(float f){
  unsigned u = bcu(f);
  unsigned r = (u + 0x7FFFu + ((u >> 16) & 1u)) >> 16;
  return r;
}

// ---------------- W transpose + split to bf16 hi/lo: Wt[n][k] ----------------
__global__ __launch_bounds__(256) void prep_wt(const float* __restrict__ W1,
                                               const float* __restrict__ W2,
                                               const float* __restrict__ W3,
                                               short* __restrict__ Wt) {
  int idx = blockIdx.x * 256 + threadIdx.x;
  int L = idx >> 14, r = idx & 16383;
  int k = r >> 7, n = r & 127;
  const float* W = (L == 0) ? W1 : (L == 1) ? W2 : W3;
  float w = W[k*128 + n];
  unsigned hi = rtn16(w);
  float lo = w - bcf(hi << 16);
  short* Whi = Wt + (size_t)L * 2 * 16384;
  short* Wlo = Whi + 16384;
  Whi[n*128 + k] = (short)hi;
  Wlo[n*128 + k] = (short)(bcu(lo) >> 16);
}

// sort compare-exchange step (descending key, ascending idx on ties)
#define BSTEP(OK, OI, KKc, Jc) do { \
  bool iLess = ((tid & (Jc)) == 0); \
  bool descR = ((tid & (KKc)) == 0); \
  bool myFirst = (kf > (OK)) || (kf == (OK) && ki < (OI)); \
  bool keep = (iLess == descR) ? myFirst : !myFirst; \
  if (!keep) { kf = (OK); ki = (OI); } \
} while (0)

// single-wave exclusive scan of cntA -> rloc + curA; rloc[NPG] = total
#define WAVE0_SCAN() do { \
  if (wid == 0) { \
    int b4 = lane*4; \
    int c0=cntA[b4+0], c1=cntA[b4+1], c2=cntA[b4+2], c3=cntA[b4+3]; \
    int tot = c0+c1+c2+c3; \
    int run = tot; \
    _Pragma("unroll") \
    for (int off=1; off<64; off<<=1) { \
      int u = __shfl_up(run, off); \
      run += (lane >= off) ? u : 0; \
    } \
    int st = run - tot; \
    rloc[b4+0]=(unsigned short)st; \
    rloc[b4+1]=(unsigned short)(st+c0); \
    rloc[b4+2]=(unsigned short)(st+c0+c1); \
    rloc[b4+3]=(unsigned short)(st+c0+c1+c2); \
    curA[b4+0]=st; curA[b4+1]=st+c0; curA[b4+2]=st+c0+c1; curA[b4+3]=st+c0+c1+c2; \
    if (lane == 63) rloc[NPG] = (unsigned short)run; \
  } \
} while (0)

// ---------------- whole network, one block per graph ----------------
// __launch_bounds__(1024, 4): 4 waves/EU min -> VGPR cap 128 (we are
// LDS-limited to 1 block/CU = 4 waves/EU anyway); kills the 24 MB scratch spill.
__global__ __launch_bounds__(1024, 4)
void fused_net(
    const float* __restrict__ x,
    const int* __restrict__ srcI, const int* __restrict__ dstI,
    const short* __restrict__ WtAll,
    const float* __restrict__ b1, const float* __restrict__ Ws1, const float* __restrict__ bs1,
    const float* __restrict__ b2, const float* __restrict__ Ws2, const float* __restrict__ bs2,
    const float* __restrict__ b3, const float* __restrict__ Ws3, const float* __restrict__ bs3,
    const float* __restrict__ Wl1, const float* __restrict__ bl1,
    const float* __restrict__ Wl2, const float* __restrict__ bl2,
    const float* __restrict__ Wl3, const float* __restrict__ bl3,
    float* __restrict__ out)
{
  __shared__ __align__(16) short hpair[2][NPG*PSTR];   // 139264 B; aliased by tbufF
  __shared__ unsigned char colS[EPG2 + 8];             // compacted CSR col, by dst, incl self
  __shared__ unsigned short rloc[NPG+2];
  __shared__ unsigned mbits[8];                        // survivor bitmask
  __shared__ float dinv[NPG];
  __shared__ __align__(16) float bvec[HF];
  __shared__ __align__(16) float wsv[HF];
  __shared__ float score[NPG];
  __shared__ float tscale[NPG];                        // tq scratch / tanh scale
  __shared__ float nmf[NPG];
  __shared__ float skey[NPG];
  __shared__ int   sidx[NPG];
  __shared__ __align__(16) float red[1024];            // partials / readout / MLP scratch
  __shared__ float zacc[2*HF];

  float* tbufF = (float*)&hpair[0][0];                 // [node][FSTR] f32 (G rows), alias
  short* hp0 = &hpair[0][0];
  short* hp1 = &hpair[1][0];
  int* cntA = (int*)skey;                              // CSR-build aliases (sort idle)
  int* curA = sidx;

  int tid = threadIdx.x;
  int g = blockIdx.x;
  size_t nbase = (size_t)g * NPG;
  int lane = tid & 63, wid = tid >> 6;
  int v = tid >> 2, fq = tid & 3, cb = fq * 4;

  // ---- stage x into bf16 hi/lo pair ----
  const float4* X4 = (const float4*)(x + nbase*HF);
  #pragma unroll
  for (int i = 0; i < 8; ++i) {
    int f4 = tid + i*1024;
    int r = f4 >> 5, kq = f4 & 31;
    float4 val = X4[f4];
    unsigned rx = rtn16(val.x), ry = rtn16(val.y), rz = rtn16(val.z), rw = rtn16(val.w);
    uint2 ph; ph.x = rx | (ry << 16); ph.y = rz | (rw << 16);
    float lx = val.x - bcf(rx << 16), ly = val.y - bcf(ry << 16);
    float lz = val.z - bcf(rz << 16), lw = val.w - bcf(rw << 16);
    uint2 pl; pl.x = (bcu(lx) >> 16) | (bcu(ly) & 0xFFFF0000u);
    pl.y = (bcu(lz) >> 16) | (bcu(lw) & 0xFFFF0000u);
    *(uint2*)&hp0[r*PSTR + kq*4] = ph;
    *(uint2*)&hp1[r*PSTR + kq*4] = pl;
  }

  // ---- edges into registers (kept all layers) ----
  int nb = g * NPG;
  int dloc[4], sloc[4];
  #pragma unroll
  for (int it = 0; it < 4; ++it) {
    int e = g*EPG + tid + it*1024;
    dloc[it] = dstI[e] - nb;
    sloc[it] = srcI[e] - nb;
  }

  // ---- initial CSR build (all alive, +1 self slot per node) ----
  if (tid < NPG) cntA[tid] = 1;
  if (tid < 8) mbits[tid] = 0xFFFFFFFFu;
  __syncthreads();
  #pragma unroll
  for (int it = 0; it < 4; ++it) atomicAdd(&cntA[dloc[it]], 1);
  __syncthreads();
  WAVE0_SCAN();
  __syncthreads();
  #pragma unroll
  for (int it = 0; it < 4; ++it) {
    int slot = atomicAdd(&curA[dloc[it]], 1);
    colS[slot] = (unsigned char)sloc[it];
  }
  if (tid < NPG) colS[rloc[tid+1] - 1] = (unsigned char)tid;  // self in last slot

  // ---- 3 GCN+SAGPool layers ----
  #pragma unroll 1
  for (int L = 0; L < 3; ++L) {
    const short* Whi = WtAll + (size_t)L * 2 * 16384;
    const short* Wlo = Whi + 16384;
    const float* bias = (L == 0) ? b1 : (L == 1) ? b2 : b3;
    const float* Wsc  = (L == 0) ? Ws1 : (L == 1) ? Ws2 : Ws3;
    const float* bscp = (L == 0) ? bs1 : (L == 1) ? bs2 : bs3;
    int K = NPG >> (L + 1);          // 128, 64, 32

    __syncthreads();   // B0: pack + CSR (re)build complete

    // ---- params + dinv (compacted row length IS the degree incl self) ----
    if (tid < HF) { bvec[tid] = bias[tid]; wsv[tid] = Wsc[tid]; }
    if (tid < NPG) {
      int c = (int)rloc[tid+1] - (int)rloc[tid];
      bool alive = (mbits[tid>>5] >> (tid&31)) & 1;
      dinv[tid] = alive ? (1.0f / sqrtf((float)c)) : 0.0f;
    }

    // ---- transform: G = dinv * (h @ W)  (MFMA on resident bf16 pair, in place) ----
    {
      int rg = wid & 7, cg = wid >> 3;
      int lr = lane & 15, lk8 = (lane >> 4) * 8;
      f32x4 tacc[2][4] = {};
      #pragma unroll
      for (int kc = 0; kc < 4; ++kc) {
        int k0 = kc*32 + lk8;
        bf16x8 ah[2], al[2];
        #pragma unroll
        for (int rt = 0; rt < 2; ++rt) {
          int row = rg*32 + rt*16 + lr;
          ah[rt] = *(const bf16x8*)&hp0[row*PSTR + k0];
          al[rt] = *(const bf16x8*)&hp1[row*PSTR + k0];
        }
        #pragma unroll
        for (int ct = 0; ct < 4; ++ct) {
          int n = cg*64 + ct*16 + lr;
          bf16x8 bh = *(const bf16x8*)&Whi[n*HF + k0];
          bf16x8 bl = *(const bf16x8*)&Wlo[n*HF + k0];
          #pragma unroll
          for (int rt = 0; rt < 2; ++rt) {
            tacc[rt][ct] = __builtin_amdgcn_mfma_f32_16x16x32_bf16(ah[rt], bh, tacc[rt][ct], 0, 0, 0);
            tacc[rt][ct] = __builtin_amdgcn_mfma_f32_16x16x32_bf16(al[rt], bh, tacc[rt][ct], 0, 0, 0);
            tacc[rt][ct] = __builtin_amdgcn_mfma_f32_16x16x32_bf16(ah[rt], bl, tacc[rt][ct], 0, 0, 0);
          }
        }
      }
      __syncthreads();   // B1: all pair reads done (dinv also complete)
      #pragma unroll
      for (int rt = 0; rt < 2; ++rt) {
        int row0 = rg*32 + rt*16 + (lane >> 4)*4;
        float d0 = dinv[row0+0], d1 = dinv[row0+1], d2 = dinv[row0+2], d3 = dinv[row0+3];
        #pragma unroll
        for (int ct = 0; ct < 4; ++ct) {
          int c = cg*64 + ct*16 + (lane & 15);
          tbufF[(row0+0)*FSTR + c] = tacc[rt][ct][0] * d0;
          tbufF[(row0+1)*FSTR + c] = tacc[rt][ct][1] * d1;
          tbufF[(row0+2)*FSTR + c] = tacc[rt][ct][2] * d2;
          tbufF[(row0+3)*FSTR + c] = tacc[rt][ct][3] * d3;
        }
      }
    }
    __syncthreads();   // B2: G ready

    // ---- aggregation: plain sum of G rows over compacted edges (incl self) ----
    float4 hv[8];
    {
      float4 acc[8] = {};
      int e0 = rloc[v], e1 = rloc[v+1];
      int e = e0;
      for (; e + 1 < e1; e += 2) {
        int s0 = colS[e], s1 = colS[e+1];
        const float* g0 = &tbufF[s0*FSTR + cb];
        const float* g1 = &tbufF[s1*FSTR + cb];
        #pragma unroll
        for (int i = 0; i < 8; ++i) {
          float4 t0 = *(const float4*)&g0[i*16];
          float4 t1 = *(const float4*)&g1[i*16];
          acc[i].x += t0.x; acc[i].y += t0.y; acc[i].z += t0.z; acc[i].w += t0.w;
          acc[i].x += t1.x; acc[i].y += t1.y; acc[i].z += t1.z; acc[i].w += t1.w;
        }
      }
      if (e < e1) {
        const float* g0 = &tbufF[(int)colS[e]*FSTR + cb];
        #pragma unroll
        for (int i = 0; i < 8; ++i) {
          float4 t0 = *(const float4*)&g0[i*16];
          acc[i].x += t0.x; acc[i].y += t0.y; acc[i].z += t0.z; acc[i].w += t0.w;
        }
      }
      float dv = dinv[v];
      float p = 0.f;
      #pragma unroll
      for (int i = 0; i < 8; ++i) {
        int ci = i*16 + cb;
        float4 bv = *(const float4*)&bvec[ci];
        float4 wv = *(const float4*)&wsv[ci];
        float4 a;
        a.x = fmaxf(fmaf(dv, acc[i].x, bv.x), 0.f);
        a.y = fmaxf(fmaf(dv, acc[i].y, bv.y), 0.f);
        a.z = fmaxf(fmaf(dv, acc[i].z, bv.z), 0.f);
        a.w = fmaxf(fmaf(dv, acc[i].w, bv.w), 0.f);
        hv[i] = a;
        p += a.x*wv.x + a.y*wv.y + a.z*wv.z + a.w*wv.w;
      }
      red[tid] = p;
    }
    __syncthreads();   // B3: score partials ready, G reads done
    if (tid < NPG) {
      float4 q = *(const float4*)&red[tid*4];
      tscale[tid] = ((q.x + q.y) + (q.z + q.w)) * dinv[tid];   // tq = (h.Ws)*dinv
      nmf[tid] = 0.f;
    }
    __syncthreads();   // B4
    if (tid < NPG) {
      int e0 = rloc[tid], e1 = rloc[tid+1];
      float sa = 0.f;
      for (int e = e0; e < e1; ++e) sa += tscale[colS[e]];
      score[tid] = dinv[tid] * sa + bscp[0];
    }
    __syncthreads();   // B5: scores ready

    // ---- register bitonic top-K (4 waves), desc score / asc idx ----
    float kf = -INFINITY; int ki = tid;
    if (tid < NPG) {
      kf = (dinv[tid] > 0.f) ? score[tid] : -INFINITY;
      for (int kk = 2; kk <= 64; kk <<= 1)
        for (int j = kk >> 1; j > 0; j >>= 1) {
          float ok = __shfl_xor(kf, j);
          int   oi = __shfl_xor(ki, j);
          BSTEP(ok, oi, kk, j);
        }
    }
    if (tid < NPG) { skey[tid] = kf; sidx[tid] = ki; }
    else if (tid < NPG + 8) mbits[tid - NPG] = 0u;     // clear mask mid-sort (idle waves)
    __syncthreads();
    if (tid < NPG) {
      int l = tid ^ 64; float ok = skey[l]; int oi = sidx[l];
      BSTEP(ok, oi, 128, 64);
      for (int j = 32; j > 0; j >>= 1) {
        float sk = __shfl_xor(kf, j); int si = __shfl_xor(ki, j);
        BSTEP(sk, si, 128, j);
      }
    }
    __syncthreads();
    if (tid < NPG) { skey[tid] = kf; sidx[tid] = ki; }
    __syncthreads();
    if (tid < NPG) {
      int l = tid ^ 128; float ok = skey[l]; int oi = sidx[l];
      BSTEP(ok, oi, 256, 128);
    }
    __syncthreads();
    if (tid < NPG) { skey[tid] = kf; sidx[tid] = ki; }
    __syncthreads();
    if (tid < NPG) {
      int l = tid ^ 64; float ok = skey[l]; int oi = sidx[l];
      BSTEP(ok, oi, 256, 64);
      for (int j = 32; j > 0; j >>= 1) {
        float sk = __shfl_xor(kf, j); int si = __shfl_xor(ki, j);
        BSTEP(sk, si, 256, j);
      }
    }
    if (tid < K) { nmf[ki] = 1.0f; atomicOr(&mbits[ki>>5], 1u << (ki&31)); }
    __syncthreads();
    if (tid < NPG) tscale[tid] = tanhf(score[tid]) * nmf[tid];
    __syncthreads();

    // ---- scale (regs) + write f32 for readout ----
    {
      float ts = tscale[v];
      #pragma unroll
      for (int i = 0; i < 8; ++i) {
        hv[i].x *= ts; hv[i].y *= ts; hv[i].z *= ts; hv[i].w *= ts;
        *(float4*)&tbufF[v*FSTR + i*16 + cb] = hv[i];
      }
    }
    __syncthreads();

    // ---- readout: max & mean over selected nodes -> zacc ----
    {
      int f = tid & 127, vg = tid >> 7;
      float mx = -INFINITY, sm = 0.f;
      for (int vr = 0; vr < 32; ++vr) {
        int vv = vg*32 + vr;
        float val = tbufF[vv*FSTR + f];
        if (nmf[vv] > 0.f) { mx = fmaxf(mx, val); sm += val; }
      }
      red[vg*HF + f] = mx;
      __syncthreads();
      if (tid < HF) {
        float zm = red[tid];
        #pragma unroll
        for (int q = 1; q < 8; ++q) zm = fmaxf(zm, red[q*HF + tid]);
        if (L == 0) zacc[tid] = zm; else zacc[tid] += zm;
      }
      __syncthreads();
      red[vg*HF + f] = sm;
      __syncthreads();
      if (tid < HF) {
        float zs = red[tid];
        #pragma unroll
        for (int q = 1; q < 8; ++q) zs += red[q*HF + tid];
        float mn = zs / (float)K;
        if (L == 0) zacc[HF + tid] = mn; else zacc[HF + tid] += mn;
      }
      __syncthreads();   // all tbufF/red reads done
    }

    if (L < 2) {
      // ---- pack scaled h into bf16 pair for next layer ----
      #pragma unroll
      for (int i = 0; i < 8; ++i) {
        int ci = i*16 + cb;
        float4 val = hv[i];
        unsigned rx = rtn16(val.x), ry = rtn16(val.y), rz = rtn16(val.z), rw = rtn16(val.w);
        uint2 ph; ph.x = rx | (ry << 16); ph.y = rz | (rw << 16);
        float lx = val.x - bcf(rx << 16), ly = val.y - bcf(ry << 16);
        float lz = val.z - bcf(rz << 16), lw = val.w - bcf(rw << 16);
        uint2 pl; pl.x = (bcu(lx) >> 16) | (bcu(ly) & 0xFFFF0000u);
        pl.y = (bcu(lz) >> 16) | (bcu(lw) & 0xFFFF0000u);
        *(uint2*)&hp0[v*PSTR + ci] = ph;
        *(uint2*)&hp1[v*PSTR + ci] = pl;
      }

      // ---- rebuild compacted CSR for the new mask (both endpoints alive) ----
      bool keep[4];
      #pragma unroll
      for (int it = 0; it < 4; ++it) {
        keep[it] = (((mbits[dloc[it]>>5] >> (dloc[it]&31)) & 1) &
                    ((mbits[sloc[it]>>5] >> (sloc[it]&31)) & 1)) != 0;
      }
      bool aliveMe = false;
      if (tid < NPG) aliveMe = (mbits[tid>>5] >> (tid&31)) & 1;
      __syncthreads();               // mbits reads done; cntA/curA (skey/sidx) free
      if (tid < NPG) cntA[tid] = aliveMe ? 1 : 0;
      __syncthreads();
      #pragma unroll
      for (int it = 0; it < 4; ++it)
        if (keep[it]) atomicAdd(&cntA[dloc[it]], 1);
      __syncthreads();
      WAVE0_SCAN();
      __syncthreads();
      #pragma unroll
      for (int it = 0; it < 4; ++it) {
        if (keep[it]) {
          int slot = atomicAdd(&curA[dloc[it]], 1);
          colS[slot] = (unsigned char)sloc[it];
        }
      }
      if (tid < NPG && aliveMe) colS[rloc[tid+1] - 1] = (unsigned char)tid;
      // next-layer B0 covers completion
    }
  }

  __syncthreads();

  // ---- MLP head + log_softmax ----
  {
    int o = tid & 127, kg = tid >> 7;
    float p = 0.f;
    int k0 = kg*32;
    for (int k = k0; k < k0+32; ++k) p += zacc[k]*Wl1[k*HF + o];
    red[kg*HF + o] = p;
    __syncthreads();
    if (tid < HF) {
      float a = bl1[tid];
      #pragma unroll
      for (int q = 0; q < 8; ++q) a += red[q*HF + tid];
      score[tid] = fmaxf(a, 0.f);       // h1
    }
    __syncthreads();
    if (tid < 512) {
      int o2 = tid & 63, kg2 = tid >> 6;
      float p2 = 0.f;
      int k0b = kg2*16;
      for (int k = k0b; k < k0b+16; ++k) p2 += score[k]*Wl2[k*64 + o2];
      red[kg2*64 + o2] = p2;
    }
    __syncthreads();
    if (tid < 64) {
      float a = bl2[tid];
      #pragma unroll
      for (int q = 0; q < 8; ++q) a += red[q*64 + tid];
      tscale[tid] = fmaxf(a, 0.f);      // h2
    }
    __syncthreads();
    if (tid < 10) {
      float a = bl3[tid];
      for (int k = 0; k < 64; ++k) a += tscale[k]*Wl3[k*10 + tid];
      nmf[tid] = fmaxf(a, 0.f);         // logits
    }
    __syncthreads();
    if (tid == 0) {
      float m = nmf[0];
      for (int i = 1; i < 10; ++i) m = fmaxf(m, nmf[i]);
      float s = 0.f;
      for (int i = 0; i < 10; ++i) s += expf(nmf[i] - m);
      red[0] = m; red[1] = logf(s);
    }
    __syncthreads();
    if (tid < 10) out[(size_t)g*10 + tid] = nmf[tid] - red[0] - red[1];
  }
}

extern "C" void kernel_launch(void* const* d_in, const int* in_sizes, int n_in,
                              void* d_out, int out_size, void* d_ws, size_t ws_size,
                              hipStream_t stream) {
  const float* x   = (const float*)d_in[0];
  const int*  srcI = (const int*)d_in[1];
  const int*  dstI = (const int*)d_in[2];
  const float* W1  = (const float*)d_in[3];
  const float* b1  = (const float*)d_in[4];
  const float* W2  = (const float*)d_in[5];
  const float* b2  = (const float*)d_in[6];
  const float* W3  = (const float*)d_in[7];
  const float* b3  = (const float*)d_in[8];
  const float* Ws1 = (const float*)d_in[9];
  const float* bs1 = (const float*)d_in[10];
  const float* Ws2 = (const float*)d_in[11];
  const float* bs2 = (const float*)d_in[12];
  const float* Ws3 = (const float*)d_in[13];
  const float* bs3 = (const float*)d_in[14];
  const float* Wl1 = (const float*)d_in[15];
  const float* bl1 = (const float*)d_in[16];
  const float* Wl2 = (const float*)d_in[17];
  const float* bl2 = (const float*)d_in[18];
  const float* Wl3 = (const float*)d_in[19];
  const float* bl3 = (const float*)d_in[20];
  float* out = (float*)d_out;

  short* WtAll = (short*)d_ws;   // 3 * 2 * 16384 shorts = 192 KB

  prep_wt<<<192, 256, 0, stream>>>(W1, W2, W3, WtAll);
  fused_net<<<NGRAPH, 1024, 0, stream>>>(x, srcI, dstI, WtAll,
                                         b1, Ws1, bs1, b2, Ws2, bs2, b3, Ws3, bs3,
                                         Wl1, bl1, Wl2, bl2, Wl3, bl3, out);
}

// Round 11
// 93.686 us; speedup vs baseline: 2.1971x; 1.4223x over previous
//
#include <hip/hip_runtime.h>
#include <math.h>

#define NGRAPH 256
#define NPG 256
#define HF 128
#define EPG 4096      // real edges per graph
#define EPG2 4352     // max CSR slots incl one self-edge per node
#define FSTR 132      // f32 row stride in tbufF (aliases hpair)
#define PSTR 136      // short row stride in hpair

typedef __attribute__((ext_vector_type(8))) short bf16x8;
typedef __attribute__((ext_vector_type(4))) float f32x4;

template<int N> struct IC { static constexpr int value = N; };
template<bool B> struct BC { static constexpr bool value = B; };

static __device__ __forceinline__ unsigned bcu(float f){ return __builtin_bit_cast(unsigned, f); }
static __device__ __forceinline__ float bcf(unsigned u){ return __builtin_bit_cast(float, u); }
static __device__ __forceinline__ unsigned rtn16(float f){
  unsigned u = bcu(f);
  return (u + 0x7FFFu + ((u >> 16) & 1u)) >> 16;
}

// ---------------- W transpose + split to bf16 hi/lo: Wt[n][k] ----------------
__global__ __launch_bounds__(256) void prep_wt(const float* __restrict__ W1,
                                               const float* __restrict__ W2,
                                               const float* __restrict__ W3,
                                               short* __restrict__ Wt) {
  int idx = blockIdx.x * 256 + threadIdx.x;
  int L = idx >> 14, r = idx & 16383;
  int k = r >> 7, n = r & 127;
  const float* W = (L == 0) ? W1 : (L == 1) ? W2 : W3;
  float w = W[k*128 + n];
  unsigned hi = rtn16(w);
  float lo = w - bcf(hi << 16);
  short* Whi = Wt + (size_t)L * 2 * 16384;
  short* Wlo = Whi + 16384;
  Whi[n*128 + k] = (short)hi;
  Wlo[n*128 + k] = (short)(bcu(lo) >> 16);
}

// sort compare-exchange step (descending key, ascending idx on ties)
#define BSTEP(OK, OI, KKc, Jc) do { \
  bool iLess = ((tid & (Jc)) == 0); \
  bool descR = ((tid & (KKc)) == 0); \
  bool myFirst = (kf > (OK)) || (kf == (OK) && ki < (OI)); \
  bool keep = (iLess == descR) ? myFirst : !myFirst; \
  if (!keep) { kf = (OK); ki = (OI); } \
} while (0)

// single-wave exclusive scan of cntA -> rloc + curA; rloc[NPG] = total
#define WAVE0_SCAN() do { \
  if (wid == 0) { \
    int b4 = lane*4; \
    int c0=cntA[b4+0], c1=cntA[b4+1], c2=cntA[b4+2], c3=cntA[b4+3]; \
    int tot = c0+c1+c2+c3; \
    int run = tot; \
    _Pragma("unroll") \
    for (int off=1; off<64; off<<=1) { \
      int u = __shfl_up(run, off); \
      run += (lane >= off) ? u : 0; \
    } \
    int st = run - tot; \
    rloc[b4+0]=(unsigned short)st; \
    rloc[b4+1]=(unsigned short)(st+c0); \
    rloc[b4+2]=(unsigned short)(st+c0+c1); \
    rloc[b4+3]=(unsigned short)(st+c0+c1+c2); \
    curA[b4+0]=st; curA[b4+1]=st+c0; curA[b4+2]=st+c0+c1; curA[b4+3]=st+c0+c1+c2; \
    if (lane == 63) rloc[NPG] = (unsigned short)run; \
  } \
} while (0)

// ---------------- whole network, one block per graph ----------------
__global__ __launch_bounds__(1024, 4)
void fused_net(
    const float* __restrict__ x,
    const int* __restrict__ srcI, const int* __restrict__ dstI,
    const short* __restrict__ WtAll,
    const float* __restrict__ b1, const float* __restrict__ Ws1, const float* __restrict__ bs1,
    const float* __restrict__ b2, const float* __restrict__ Ws2, const float* __restrict__ bs2,
    const float* __restrict__ b3, const float* __restrict__ Ws3, const float* __restrict__ bs3,
    const float* __restrict__ Wl1, const float* __restrict__ bl1,
    const float* __restrict__ Wl2, const float* __restrict__ bl2,
    const float* __restrict__ Wl3, const float* __restrict__ bl3,
    float* __restrict__ out)
{
  __shared__ __align__(16) short hpair[2][NPG*PSTR];   // 139264 B; aliased by tbufF
  __shared__ unsigned char colS[EPG2 + 8];             // compacted CSR (current ids), incl self
  __shared__ unsigned short rloc[NPG+2];
  __shared__ unsigned selM[8];                         // selection bitmask (current ids)
  __shared__ float dinv[NPG];
  __shared__ __align__(16) float bvec[HF];
  __shared__ __align__(16) float wsv[HF];
  __shared__ float score[NPG];
  __shared__ float tscale[NPG];
  __shared__ float skey[NPG];
  __shared__ int   sidx[NPG];
  __shared__ unsigned char rank8[NPG];                 // current id -> next id (0xFF dead)
  __shared__ unsigned char lut[NPG];                   // ORIGINAL id -> current id (0xFF dead)
  __shared__ __align__(16) float red[1024];
  __shared__ float zacc[2*HF];

  float* tbufF = (float*)&hpair[0][0];                 // [row][FSTR] f32, alias
  short* hp0 = &hpair[0][0];
  short* hp1 = &hpair[1][0];
  int* cntA = (int*)skey;
  int* curA = sidx;

  int tid = threadIdx.x;
  int g = blockIdx.x;
  size_t nbase = (size_t)g * NPG;
  int lane = tid & 63, wid = tid >> 6;

  // ---- stage x into bf16 hi/lo pair ----
  const float4* X4 = (const float4*)(x + nbase*HF);
  #pragma unroll
  for (int i = 0; i < 8; ++i) {
    int f4 = tid + i*1024;
    int r = f4 >> 5, kq = f4 & 31;
    float4 val = X4[f4];
    unsigned rx = rtn16(val.x), ry = rtn16(val.y), rz = rtn16(val.z), rw = rtn16(val.w);
    uint2 ph; ph.x = rx | (ry << 16); ph.y = rz | (rw << 16);
    float lx = val.x - bcf(rx << 16), ly = val.y - bcf(ry << 16);
    float lz = val.z - bcf(rz << 16), lw = val.w - bcf(rw << 16);
    uint2 pl; pl.x = (bcu(lx) >> 16) | (bcu(ly) & 0xFFFF0000u);
    pl.y = (bcu(lz) >> 16) | (bcu(lw) & 0xFFFF0000u);
    *(uint2*)&hp0[r*PSTR + kq*4] = ph;
    *(uint2*)&hp1[r*PSTR + kq*4] = pl;
  }

  // ---- edges into registers (ORIGINAL local ids, kept all layers) ----
  int nb = g * NPG;
  int dloc[4], sloc[4];
  #pragma unroll
  for (int it = 0; it < 4; ++it) {
    int e = g*EPG + tid + it*1024;
    dloc[it] = dstI[e] - nb;
    sloc[it] = srcI[e] - nb;
  }

  // ---- initial CSR build (all alive, +1 self slot per node) + lut identity ----
  if (tid < NPG) { cntA[tid] = 1; lut[tid] = (unsigned char)tid; }
  __syncthreads();
  #pragma unroll
  for (int it = 0; it < 4; ++it) atomicAdd(&cntA[dloc[it]], 1);
  __syncthreads();
  WAVE0_SCAN();
  __syncthreads();
  #pragma unroll
  for (int it = 0; it < 4; ++it) {
    int slot = atomicAdd(&curA[dloc[it]], 1);
    colS[slot] = (unsigned char)sloc[it];
  }
  if (tid < NPG) colS[rloc[tid+1] - 1] = (unsigned char)tid;

  // ================= layer template =================
  auto run_layer = [&](auto nrc, auto kc, auto firstc, auto packc,
                       const short* Whi, const short* Wlo,
                       const float* bias, const float* Wsc, const float* bscp) {
    constexpr int NR = decltype(nrc)::value;      // rows in (compacted)
    constexpr int K  = decltype(kc)::value;       // rows out
    constexpr bool FIRST = decltype(firstc)::value;
    constexpr bool PACK  = decltype(packc)::value;
    constexpr int TPN = 1024 / NR;                // threads per node: 4,8,16
    constexpr int NI  = 32 / TPN;                 // float4s per thread: 8,4,2
    constexpr int SH  = (TPN == 4) ? 2 : ((TPN == 8) ? 3 : 4);
    int v = tid >> SH, q = tid & (TPN - 1);
    int cb0 = 4 * q;

    __syncthreads();   // B0: pair + CSR ready

    if (tid < HF) { bvec[tid] = bias[tid]; wsv[tid] = Wsc[tid]; }
    if (tid < NR) dinv[tid] = 1.0f / sqrtf((float)((int)rloc[tid+1] - (int)rloc[tid]));

    // ---- transform: G = dinv * (h @ W), rows 0..NR-1 only ----
    {
      int rg = wid & 7, cg = wid >> 3;
      bool act = (rg * 32 < NR);
      int lr = lane & 15, lk8 = (lane >> 4) * 8;
      f32x4 tacc[2][4] = {};
      if (act) {
        #pragma unroll
        for (int kc2 = 0; kc2 < 4; ++kc2) {
          int k0 = kc2*32 + lk8;
          bf16x8 ah[2], al[2];
          #pragma unroll
          for (int rt = 0; rt < 2; ++rt) {
            int row = rg*32 + rt*16 + lr;
            ah[rt] = *(const bf16x8*)&hp0[row*PSTR + k0];
            al[rt] = *(const bf16x8*)&hp1[row*PSTR + k0];
          }
          #pragma unroll
          for (int ct = 0; ct < 4; ++ct) {
            int n = cg*64 + ct*16 + lr;
            bf16x8 bh = *(const bf16x8*)&Whi[n*HF + k0];
            bf16x8 bl = *(const bf16x8*)&Wlo[n*HF + k0];
            #pragma unroll
            for (int rt = 0; rt < 2; ++rt) {
              tacc[rt][ct] = __builtin_amdgcn_mfma_f32_16x16x32_bf16(ah[rt], bh, tacc[rt][ct], 0, 0, 0);
              tacc[rt][ct] = __builtin_amdgcn_mfma_f32_16x16x32_bf16(al[rt], bh, tacc[rt][ct], 0, 0, 0);
              tacc[rt][ct] = __builtin_amdgcn_mfma_f32_16x16x32_bf16(ah[rt], bl, tacc[rt][ct], 0, 0, 0);
            }
          }
        }
      }
      __syncthreads();   // B1: pair reads done, dinv ready
      if (act) {
        #pragma unroll
        for (int rt = 0; rt < 2; ++rt) {
          int row0 = rg*32 + rt*16 + (lane >> 4)*4;
          float d0 = dinv[row0+0], d1 = dinv[row0+1], d2 = dinv[row0+2], d3 = dinv[row0+3];
          #pragma unroll
          for (int ct = 0; ct < 4; ++ct) {
            int c = cg*64 + ct*16 + (lane & 15);
            tbufF[(row0+0)*FSTR + c] = tacc[rt][ct][0] * d0;
            tbufF[(row0+1)*FSTR + c] = tacc[rt][ct][1] * d1;
            tbufF[(row0+2)*FSTR + c] = tacc[rt][ct][2] * d2;
            tbufF[(row0+3)*FSTR + c] = tacc[rt][ct][3] * d3;
          }
        }
      }
    }
    __syncthreads();   // B2: G ready

    // ---- aggregation: TPN threads/node, plain sum over compacted edges ----
    float4 hv[NI];
    {
      float4 acc[NI];
      #pragma unroll
      for (int j = 0; j < NI; ++j) { acc[j].x = acc[j].y = acc[j].z = acc[j].w = 0.f; }
      int e0 = rloc[v], e1 = rloc[v+1];
      int e = e0;
      for (; e + 1 < e1; e += 2) {
        int s0 = colS[e], s1 = colS[e+1];
        const float* g0 = &tbufF[s0*FSTR + cb0];
        const float* g1 = &tbufF[s1*FSTR + cb0];
        #pragma unroll
        for (int j = 0; j < NI; ++j) {
          float4 t0 = *(const float4*)&g0[j*4*TPN];
          float4 t1 = *(const float4*)&g1[j*4*TPN];
          acc[j].x += t0.x + t1.x; acc[j].y += t0.y + t1.y;
          acc[j].z += t0.z + t1.z; acc[j].w += t0.w + t1.w;
        }
      }
      if (e < e1) {
        const float* g0 = &tbufF[(int)colS[e]*FSTR + cb0];
        #pragma unroll
        for (int j = 0; j < NI; ++j) {
          float4 t0 = *(const float4*)&g0[j*4*TPN];
          acc[j].x += t0.x; acc[j].y += t0.y; acc[j].z += t0.z; acc[j].w += t0.w;
        }
      }
      float dv = dinv[v];
      float p = 0.f;
      #pragma unroll
      for (int j = 0; j < NI; ++j) {
        int ci = cb0 + j*4*TPN;
        float4 bv = *(const float4*)&bvec[ci];
        float4 wv = *(const float4*)&wsv[ci];
        float4 a;
        a.x = fmaxf(fmaf(dv, acc[j].x, bv.x), 0.f);
        a.y = fmaxf(fmaf(dv, acc[j].y, bv.y), 0.f);
        a.z = fmaxf(fmaf(dv, acc[j].z, bv.z), 0.f);
        a.w = fmaxf(fmaf(dv, acc[j].w, bv.w), 0.f);
        hv[j] = a;
        p += a.x*wv.x + a.y*wv.y + a.z*wv.z + a.w*wv.w;
      }
      red[tid] = p;
    }
    __syncthreads();   // B3
    if (tid < NR) {
      float s4 = 0.f;
      #pragma unroll
      for (int t = 0; t < TPN/4; ++t) {
        float4 qd = *(const float4*)&red[tid*TPN + 4*t];
        s4 += (qd.x + qd.y) + (qd.z + qd.w);
      }
      tscale[tid] = s4 * dinv[tid];          // tq
    }
    __syncthreads();   // B4
    if (tid < NR) {
      int e0 = rloc[tid], e1 = rloc[tid+1];
      float sa = 0.f;
      for (int e = e0; e < e1; ++e) sa += tscale[colS[e]];
      score[tid] = dinv[tid] * sa + bscp[0];
    }
    __syncthreads();   // B5

    // ---- top-K bitonic sort over NR, desc score / asc id ----
    float kf = -INFINITY; int ki = tid;
    if (tid < NR) {
      kf = score[tid];
      for (int kk = 2; kk <= 64; kk <<= 1)
        for (int j = kk >> 1; j > 0; j >>= 1) {
          float ok = __shfl_xor(kf, j);
          int   oi = __shfl_xor(ki, j);
          BSTEP(ok, oi, kk, j);
        }
    } else if (tid < NR + 8) selM[tid - NR] = 0u;   // clear selection mask (idle threads)

    if constexpr (NR == 256) {
      if (tid < NR) { skey[tid] = kf; sidx[tid] = ki; }
      __syncthreads();
      if (tid < NR) {
        int l = tid ^ 64; float ok = skey[l]; int oi = sidx[l];
        BSTEP(ok, oi, 128, 64);
        for (int j = 32; j > 0; j >>= 1) {
          float sk = __shfl_xor(kf, j); int si = __shfl_xor(ki, j);
          BSTEP(sk, si, 128, j);
        }
      }
      __syncthreads();
      if (tid < NR) { skey[tid] = kf; sidx[tid] = ki; }
      __syncthreads();
      if (tid < NR) {
        int l = tid ^ 128; float ok = skey[l]; int oi = sidx[l];
        BSTEP(ok, oi, 256, 128);
      }
      __syncthreads();
      if (tid < NR) { skey[tid] = kf; sidx[tid] = ki; }
      __syncthreads();
      if (tid < NR) {
        int l = tid ^ 64; float ok = skey[l]; int oi = sidx[l];
        BSTEP(ok, oi, 256, 64);
        for (int j = 32; j > 0; j >>= 1) {
          float sk = __shfl_xor(kf, j); int si = __shfl_xor(ki, j);
          BSTEP(sk, si, 256, j);
        }
      }
    } else if constexpr (NR == 128) {
      if (tid < NR) { skey[tid] = kf; sidx[tid] = ki; }
      __syncthreads();
      if (tid < NR) {
        int l = tid ^ 64; float ok = skey[l]; int oi = sidx[l];
        BSTEP(ok, oi, 128, 64);
        for (int j = 32; j > 0; j >>= 1) {
          float sk = __shfl_xor(kf, j); int si = __shfl_xor(ki, j);
          BSTEP(sk, si, 128, j);
        }
      }
    }
    if constexpr (NR == 64) __syncthreads();       // separate clear from publish
    if constexpr (NR != 64 && NR != 256) __syncthreads();
    if (tid < K) atomicOr(&selM[ki >> 5], 1u << (ki & 31));
    __syncthreads();   // B6: selection published

    // ---- rank (order-preserving compaction) + tanh scale ----
    if (tid < NR) {
      unsigned wsel = selM[tid >> 5];
      bool sel = (wsel >> (tid & 31)) & 1;
      int r = __popc(wsel & ((1u << (tid & 31)) - 1u));
      for (int w = 0; w < (tid >> 5); ++w) r += __popc(selM[w]);
      rank8[tid] = sel ? (unsigned char)r : (unsigned char)0xFF;
      tscale[tid] = sel ? tanhf(score[tid]) : 0.f;
    }
    __syncthreads();   // B7: rank8/tscale ready
    if (tid < NPG) {
      int lv = lut[tid];
      lut[tid] = (lv < NR) ? rank8[lv] : (unsigned char)0xFF;
    }

    // ---- scale + write f32 h' at NEW (compacted) rows ----
    int rk = rank8[v];
    {
      float ts = tscale[v];
      if (rk != 0xFF) {
        #pragma unroll
        for (int j = 0; j < NI; ++j) {
          hv[j].x *= ts; hv[j].y *= ts; hv[j].z *= ts; hv[j].w *= ts;
          *(float4*)&tbufF[rk*FSTR + cb0 + j*4*TPN] = hv[j];
        }
      }
    }
    __syncthreads();   // B8: h' f32 ready (rows 0..K-1)

    // ---- readout over K contiguous rows -> zacc ----
    {
      constexpr int RPG = K / 8;
      int f = tid & 127, vg = tid >> 7;
      float mx = -INFINITY, sm = 0.f;
      #pragma unroll
      for (int vr = 0; vr < RPG; ++vr) {
        float val = tbufF[(vg*RPG + vr)*FSTR + f];
        mx = fmaxf(mx, val); sm += val;
      }
      red[vg*HF + f] = mx;
      __syncthreads();
      if (tid < HF) {
        float zm = red[tid];
        #pragma unroll
        for (int q2 = 1; q2 < 8; ++q2) zm = fmaxf(zm, red[q2*HF + tid]);
        if (FIRST) zacc[tid] = zm; else zacc[tid] += zm;
      }
      __syncthreads();
      red[vg*HF + f] = sm;
      __syncthreads();
      if (tid < HF) {
        float zs = red[tid];
        #pragma unroll
        for (int q2 = 1; q2 < 8; ++q2) zs += red[q2*HF + tid];
        float mn = zs / (float)K;
        if (FIRST) zacc[HF + tid] = mn; else zacc[HF + tid] += mn;
      }
      __syncthreads();   // tbufF reads done
    }

    if constexpr (PACK) {
      // ---- pack scaled h' into bf16 pair at NEW rows ----
      if (rk != 0xFF) {
        #pragma unroll
        for (int j = 0; j < NI; ++j) {
          int ci = cb0 + j*4*TPN;
          float4 val = hv[j];
          unsigned rx = rtn16(val.x), ry = rtn16(val.y), rz = rtn16(val.z), rw = rtn16(val.w);
          uint2 ph; ph.x = rx | (ry << 16); ph.y = rz | (rw << 16);
          float lx = val.x - bcf(rx << 16), ly = val.y - bcf(ry << 16);
          float lz = val.z - bcf(rz << 16), lw = val.w - bcf(rw << 16);
          uint2 pl; pl.x = (bcu(lx) >> 16) | (bcu(ly) & 0xFFFF0000u);
          pl.y = (bcu(lz) >> 16) | (bcu(lw) & 0xFFFF0000u);
          *(uint2*)&hp0[rk*PSTR + ci] = ph;
          *(uint2*)&hp1[rk*PSTR + ci] = pl;
        }
      }

      // ---- rebuild CSR in NEW id space (K rows) ----
      if (tid < K) cntA[tid] = 1; else if (tid < NPG) cntA[tid] = 0;
      __syncthreads();
      #pragma unroll
      for (int it = 0; it < 4; ++it) {
        int d2 = lut[dloc[it]], s2 = lut[sloc[it]];
        if (d2 < K && s2 < K) atomicAdd(&cntA[d2], 1);
      }
      __syncthreads();
      WAVE0_SCAN();
      __syncthreads();
      #pragma unroll
      for (int it = 0; it < 4; ++it) {
        int d2 = lut[dloc[it]], s2 = lut[sloc[it]];
        if (d2 < K && s2 < K) {
          int slot = atomicAdd(&curA[d2], 1);
          colS[slot] = (unsigned char)s2;
        }
      }
      if (tid < K) colS[rloc[tid+1] - 1] = (unsigned char)tid;
      // next layer's B0 covers visibility
    }
  };

  run_layer(IC<256>{}, IC<128>{}, BC<true>{},  BC<true>{},
            WtAll,         WtAll + 16384, b1, Ws1, bs1);
  run_layer(IC<128>{}, IC<64>{},  BC<false>{}, BC<true>{},
            WtAll + 32768, WtAll + 49152, b2, Ws2, bs2);
  run_layer(IC<64>{},  IC<32>{},  BC<false>{}, BC<false>{},
            WtAll + 65536, WtAll + 81920, b3, Ws3, bs3);

  __syncthreads();

  // ---- MLP head + log_softmax ----
  {
    int o = tid & 127, kg = tid >> 7;
    float p = 0.f;
    int k0 = kg*32;
    for (int k = k0; k < k0+32; ++k) p += zacc[k]*Wl1[k*HF + o];
    red[kg*HF + o] = p;
    __syncthreads();
    if (tid < HF) {
      float a = bl1[tid];
      #pragma unroll
      for (int q2 = 0; q2 < 8; ++q2) a += red[q2*HF + tid];
      score[tid] = fmaxf(a, 0.f);       // h1
    }
    __syncthreads();
    if (tid < 512) {
      int o2 = tid & 63, kg2 = tid >> 6;
      float p2 = 0.f;
      int k0b = kg2*16;
      for (int k = k0b; k < k0b+16; ++k) p2 += score[k]*Wl2[k*64 + o2];
      red[kg2*64 + o2] = p2;
    }
    __syncthreads();
    if (tid < 64) {
      float a = bl2[tid];
      #pragma unroll
      for (int q2 = 0; q2 < 8; ++q2) a += red[q2*64 + tid];
      tscale[tid] = fmaxf(a, 0.f);      // h2
    }
    __syncthreads();
    if (tid < 10) {
      float a = bl3[tid];
      for (int k = 0; k < 64; ++k) a += tscale[k]*Wl3[k*10 + tid];
      dinv[tid] = fmaxf(a, 0.f);        // logits
    }
    __syncthreads();
    if (tid == 0) {
      float m = dinv[0];
      for (int i = 1; i < 10; ++i) m = fmaxf(m, dinv[i]);
      float s = 0.f;
      for (int i = 0; i < 10; ++i) s += expf(dinv[i] - m);
      red[0] = m; red[1] = logf(s);
    }
    __syncthreads();
    if (tid < 10) out[(size_t)g*10 + tid] = dinv[tid] - red[0] - red[1];
  }
}

extern "C" void kernel_launch(void* const* d_in, const int* in_sizes, int n_in,
                              void* d_out, int out_size, void* d_ws, size_t ws_size,
                              hipStream_t stream) {
  const float* x   = (const float*)d_in[0];
  const int*  srcI = (const int*)d_in[1];
  const int*  dstI = (const int*)d_in[2];
  const float* W1  = (const float*)d_in[3];
  const float* b1  = (const float*)d_in[4];
  const float* W2  = (const float*)d_in[5];
  const float* b2  = (const float*)d_in[6];
  const float* W3  = (const float*)d_in[7];
  const float* b3  = (const float*)d_in[8];
  const float* Ws1 = (const float*)d_in[9];
  const float* bs1 = (const float*)d_in[10];
  const float* Ws2 = (const float*)d_in[11];
  const float* bs2 = (const float*)d_in[12];
  const float* Ws3 = (const float*)d_in[13];
  const float* bs3 = (const float*)d_in[14];
  const float* Wl1 = (const float*)d_in[15];
  const float* bl1 = (const float*)d_in[16];
  const float* Wl2 = (const float*)d_in[17];
  const float* bl2 = (const float*)d_in[18];
  const float* Wl3 = (const float*)d_in[19];
  const float* bl3 = (const float*)d_in[20];
  float* out = (float*)d_out;

  short* WtAll = (short*)d_ws;   // 3 * 2 * 16384 shorts = 192 KB

  prep_wt<<<192, 256, 0, stream>>>(W1, W2, W3, WtAll);
  fused_net<<<NGRAPH, 1024, 0, stream>>>(x, srcI, dstI, WtAll,
                                         b1, Ws1, bs1, b2, Ws2, bs2, b3, Ws3, bs3,
                                         Wl1, bl1, Wl2, bl2, Wl3, bl3, out);
}

// Round 12
// 84.067 us; speedup vs baseline: 2.4485x; 1.1144x over previous
//
#include <hip/hip_runtime.h>
#include <math.h>

#define NGRAPH 256
#define NPG 256
#define HF 128
#define EPG 4096      // real edges per graph
#define EPG2 4352     // max CSR slots incl one self-edge per node
#define FSTR 132      // f32 row stride in tbufF (aliases hpair)
#define PSTR 136      // short row stride in hpair

typedef __attribute__((ext_vector_type(8))) short bf16x8;
typedef __attribute__((ext_vector_type(4))) float f32x4;

template<int N> struct IC { static constexpr int value = N; };
template<bool B> struct BC { static constexpr bool value = B; };

static __device__ __forceinline__ unsigned bcu(float f){ return __builtin_bit_cast(unsigned, f); }
static __device__ __forceinline__ float bcf(unsigned u){ return __builtin_bit_cast(float, u); }
static __device__ __forceinline__ unsigned rtn16(float f){
  unsigned u = bcu(f);
  return (u + 0x7FFFu + ((u >> 16) & 1u)) >> 16;
}

// ---------------- W transpose + split to bf16 hi/lo: Wt[n][k] ----------------
__global__ __launch_bounds__(256) void prep_wt(const float* __restrict__ W1,
                                               const float* __restrict__ W2,
                                               const float* __restrict__ W3,
                                               short* __restrict__ Wt) {
  int idx = blockIdx.x * 256 + threadIdx.x;
  int L = idx >> 14, r = idx & 16383;
  int k = r >> 7, n = r & 127;
  const float* W = (L == 0) ? W1 : (L == 1) ? W2 : W3;
  float w = W[k*128 + n];
  unsigned hi = rtn16(w);
  float lo = w - bcf(hi << 16);
  short* Whi = Wt + (size_t)L * 2 * 16384;
  short* Wlo = Whi + 16384;
  Whi[n*128 + k] = (short)hi;
  Wlo[n*128 + k] = (short)(bcu(lo) >> 16);
}

// sort compare-exchange step (descending key, ascending idx on ties)
#define BSTEP(OK, OI, KKc, Jc) do { \
  bool iLess = ((tid & (Jc)) == 0); \
  bool descR = ((tid & (KKc)) == 0); \
  bool myFirst = (kf > (OK)) || (kf == (OK) && ki < (OI)); \
  bool keep = (iLess == descR) ? myFirst : !myFirst; \
  if (!keep) { kf = (OK); ki = (OI); } \
} while (0)

// single-wave exclusive scan of cntA -> rloc + curA; rloc[NPG] = total
#define WAVE0_SCAN() do { \
  if (wid == 0) { \
    int b4 = lane*4; \
    int c0=cntA[b4+0], c1=cntA[b4+1], c2=cntA[b4+2], c3=cntA[b4+3]; \
    int tot = c0+c1+c2+c3; \
    int run = tot; \
    _Pragma("unroll") \
    for (int off=1; off<64; off<<=1) { \
      int u = __shfl_up(run, off); \
      run += (lane >= off) ? u : 0; \
    } \
    int st = run - tot; \
    rloc[b4+0]=(unsigned short)st; \
    rloc[b4+1]=(unsigned short)(st+c0); \
    rloc[b4+2]=(unsigned short)(st+c0+c1); \
    rloc[b4+3]=(unsigned short)(st+c0+c1+c2); \
    curA[b4+0]=st; curA[b4+1]=st+c0; curA[b4+2]=st+c0+c1; curA[b4+3]=st+c0+c1+c2; \
    if (lane == 63) rloc[NPG] = (unsigned short)run; \
  } \
} while (0)

// ---------------- whole network, one block per graph ----------------
__global__ __launch_bounds__(1024, 4)
void fused_net(
    const float* __restrict__ x,
    const int* __restrict__ srcI, const int* __restrict__ dstI,
    const short* __restrict__ WtAll,
    const float* __restrict__ b1, const float* __restrict__ Ws1, const float* __restrict__ bs1,
    const float* __restrict__ b2, const float* __restrict__ Ws2, const float* __restrict__ bs2,
    const float* __restrict__ b3, const float* __restrict__ Ws3, const float* __restrict__ bs3,
    const float* __restrict__ Wl1, const float* __restrict__ bl1,
    const float* __restrict__ Wl2, const float* __restrict__ bl2,
    const float* __restrict__ Wl3, const float* __restrict__ bl3,
    float* __restrict__ out)
{
  __shared__ __align__(16) short hpair[2][NPG*PSTR];   // 139264 B; aliased by tbufF
  __shared__ unsigned char colS[EPG2 + 8];             // compacted CSR (current ids), incl self
  __shared__ unsigned short rloc[NPG+2];
  __shared__ unsigned selM[8];                         // selection bitmask (current ids)
  __shared__ float dinv[NPG];
  __shared__ __align__(16) float bvec[HF];
  __shared__ __align__(16) float wsv[HF];
  __shared__ float score[NPG];
  __shared__ float tscale[NPG];
  __shared__ float skey[NPG];
  __shared__ int   sidx[NPG];
  __shared__ unsigned char rank8[NPG];                 // current id -> next id (0xFF dead)
  __shared__ unsigned char lut[NPG];                   // ORIGINAL id -> current id (0xFF dead)
  __shared__ __align__(16) float red[1024];            // readout max / MLP scratch
  __shared__ __align__(16) float red2[1024];           // readout sum (parallel pass)
  __shared__ float zacc[2*HF];

  float* tbufF = (float*)&hpair[0][0];                 // [row][FSTR] f32, alias
  short* hp0 = &hpair[0][0];
  short* hp1 = &hpair[1][0];
  int* cntA = (int*)skey;
  int* curA = sidx;

  int tid = threadIdx.x;
  int g = blockIdx.x;
  size_t nbase = (size_t)g * NPG;
  int lane = tid & 63, wid = tid >> 6;

  // ---- stage x into bf16 hi/lo pair ----
  const float4* X4 = (const float4*)(x + nbase*HF);
  #pragma unroll
  for (int i = 0; i < 8; ++i) {
    int f4 = tid + i*1024;
    int r = f4 >> 5, kq = f4 & 31;
    float4 val = X4[f4];
    unsigned rx = rtn16(val.x), ry = rtn16(val.y), rz = rtn16(val.z), rw = rtn16(val.w);
    uint2 ph; ph.x = rx | (ry << 16); ph.y = rz | (rw << 16);
    float lx = val.x - bcf(rx << 16), ly = val.y - bcf(ry << 16);
    float lz = val.z - bcf(rz << 16), lw = val.w - bcf(rw << 16);
    uint2 pl; pl.x = (bcu(lx) >> 16) | (bcu(ly) & 0xFFFF0000u);
    pl.y = (bcu(lz) >> 16) | (bcu(lw) & 0xFFFF0000u);
    *(uint2*)&hp0[r*PSTR + kq*4] = ph;
    *(uint2*)&hp1[r*PSTR + kq*4] = pl;
  }

  // ---- edges into registers (ORIGINAL local ids, kept all layers) ----
  int nb = g * NPG;
  int dloc[4], sloc[4];
  #pragma unroll
  for (int it = 0; it < 4; ++it) {
    int e = g*EPG + tid + it*1024;
    dloc[it] = dstI[e] - nb;
    sloc[it] = srcI[e] - nb;
  }

  // ---- initial CSR build (all alive, +1 self slot per node) + lut identity ----
  if (tid < NPG) { cntA[tid] = 1; lut[tid] = (unsigned char)tid; }
  __syncthreads();
  #pragma unroll
  for (int it = 0; it < 4; ++it) atomicAdd(&cntA[dloc[it]], 1);
  __syncthreads();
  WAVE0_SCAN();
  __syncthreads();
  #pragma unroll
  for (int it = 0; it < 4; ++it) {
    int slot = atomicAdd(&curA[dloc[it]], 1);
    colS[slot] = (unsigned char)sloc[it];
  }
  if (tid < NPG) colS[rloc[tid+1] - 1] = (unsigned char)tid;

  // ================= layer template =================
  auto run_layer = [&](auto nrc, auto kc, auto firstc, auto packc,
                       const short* Whi, const short* Wlo,
                       const float* bias, const float* Wsc, const float* bscp) {
    constexpr int NR = decltype(nrc)::value;      // rows in (compacted)
    constexpr int K  = decltype(kc)::value;       // rows out
    constexpr bool FIRST = decltype(firstc)::value;
    constexpr bool PACK  = decltype(packc)::value;
    constexpr int TPN = 1024 / NR;                // threads per node: 4,8,16
    constexpr int NI  = 32 / TPN;                 // float4s per thread: 8,4,2
    constexpr int SH  = (TPN == 4) ? 2 : ((TPN == 8) ? 3 : 4);
    constexpr int RT  = NR / 64;                  // row tiles per wave: 4,2,1
    int v = tid >> SH, q = tid & (TPN - 1);
    int cb0 = 4 * q;

    __syncthreads();   // B0: pair + CSR ready

    if (tid < HF) { bvec[tid] = bias[tid]; wsv[tid] = Wsc[tid]; }
    if (tid < NR) dinv[tid] = 1.0f / sqrtf((float)((int)rloc[tid+1] - (int)rloc[tid]));

    // ---- transform: G = dinv * (h @ W), 4rg x 4cg waves, all active ----
    {
      int rg = wid & 3, cg = wid >> 2;
      int lr = lane & 15, lk8 = (lane >> 4) * 8;
      f32x4 tacc[RT][2] = {};
      #pragma unroll
      for (int kc2 = 0; kc2 < 4; ++kc2) {
        int k0 = kc2*32 + lk8;
        bf16x8 ah[RT], al[RT];
        #pragma unroll
        for (int rt = 0; rt < RT; ++rt) {
          int row = rg*(NR/4) + rt*16 + lr;
          ah[rt] = *(const bf16x8*)&hp0[row*PSTR + k0];
          al[rt] = *(const bf16x8*)&hp1[row*PSTR + k0];
        }
        #pragma unroll
        for (int ct = 0; ct < 2; ++ct) {
          int n = cg*32 + ct*16 + lr;
          bf16x8 bh = *(const bf16x8*)&Whi[n*HF + k0];
          bf16x8 bl = *(const bf16x8*)&Wlo[n*HF + k0];
          #pragma unroll
          for (int rt = 0; rt < RT; ++rt) {
            tacc[rt][ct] = __builtin_amdgcn_mfma_f32_16x16x32_bf16(ah[rt], bh, tacc[rt][ct], 0, 0, 0);
            tacc[rt][ct] = __builtin_amdgcn_mfma_f32_16x16x32_bf16(al[rt], bh, tacc[rt][ct], 0, 0, 0);
            tacc[rt][ct] = __builtin_amdgcn_mfma_f32_16x16x32_bf16(ah[rt], bl, tacc[rt][ct], 0, 0, 0);
          }
        }
      }
      __syncthreads();   // B1: pair reads done, dinv ready
      #pragma unroll
      for (int rt = 0; rt < RT; ++rt) {
        int row0 = rg*(NR/4) + rt*16 + (lane >> 4)*4;
        float d0 = dinv[row0+0], d1 = dinv[row0+1], d2 = dinv[row0+2], d3 = dinv[row0+3];
        #pragma unroll
        for (int ct = 0; ct < 2; ++ct) {
          int c = cg*32 + ct*16 + (lane & 15);
          tbufF[(row0+0)*FSTR + c] = tacc[rt][ct][0] * d0;
          tbufF[(row0+1)*FSTR + c] = tacc[rt][ct][1] * d1;
          tbufF[(row0+2)*FSTR + c] = tacc[rt][ct][2] * d2;
          tbufF[(row0+3)*FSTR + c] = tacc[rt][ct][3] * d3;
        }
      }
    }
    __syncthreads();   // B2: G ready

    // ---- aggregation: TPN threads/node, 4-deep colS prefetch ----
    float4 hv[NI];
    {
      float4 acc[NI];
      #pragma unroll
      for (int j = 0; j < NI; ++j) { acc[j].x = acc[j].y = acc[j].z = acc[j].w = 0.f; }
      int e0 = rloc[v], e1 = rloc[v+1];
      int sA = colS[e0], sB = colS[e0+1], sC = colS[e0+2], sD = colS[e0+3];
      int e = e0;
      for (; e + 1 < e1; e += 2) {
        int s0 = sA, s1 = sB;
        sA = sC; sB = sD; sC = colS[e+4]; sD = colS[e+5];
        const float* g0 = &tbufF[s0*FSTR + cb0];
        const float* g1 = &tbufF[s1*FSTR + cb0];
        #pragma unroll
        for (int j = 0; j < NI; ++j) {
          float4 t0 = *(const float4*)&g0[j*4*TPN];
          float4 t1 = *(const float4*)&g1[j*4*TPN];
          acc[j].x += t0.x + t1.x; acc[j].y += t0.y + t1.y;
          acc[j].z += t0.z + t1.z; acc[j].w += t0.w + t1.w;
        }
      }
      if (e < e1) {
        const float* g0 = &tbufF[sA*FSTR + cb0];
        #pragma unroll
        for (int j = 0; j < NI; ++j) {
          float4 t0 = *(const float4*)&g0[j*4*TPN];
          acc[j].x += t0.x; acc[j].y += t0.y; acc[j].z += t0.z; acc[j].w += t0.w;
        }
      }
      float dv = dinv[v];
      float p = 0.f;
      #pragma unroll
      for (int j = 0; j < NI; ++j) {
        int ci = cb0 + j*4*TPN;
        float4 bv = *(const float4*)&bvec[ci];
        float4 wv = *(const float4*)&wsv[ci];
        float4 a;
        a.x = fmaxf(fmaf(dv, acc[j].x, bv.x), 0.f);
        a.y = fmaxf(fmaf(dv, acc[j].y, bv.y), 0.f);
        a.z = fmaxf(fmaf(dv, acc[j].z, bv.z), 0.f);
        a.w = fmaxf(fmaf(dv, acc[j].w, bv.w), 0.f);
        hv[j] = a;
        p += a.x*wv.x + a.y*wv.y + a.z*wv.z + a.w*wv.w;
      }
      red[tid] = p;
    }
    __syncthreads();   // B3
    if (tid < NR) {
      float s4 = 0.f;
      #pragma unroll
      for (int t = 0; t < TPN/4; ++t) {
        float4 qd = *(const float4*)&red[tid*TPN + 4*t];
        s4 += (qd.x + qd.y) + (qd.z + qd.w);
      }
      tscale[tid] = s4 * dinv[tid];          // tq
    }
    __syncthreads();   // B4
    if (tid < NR) {
      int e0 = rloc[tid], e1 = rloc[tid+1];
      float sa = 0.f;
      int sA = colS[e0], sB = colS[e0+1], sC = colS[e0+2], sD = colS[e0+3];
      for (int e = e0; e < e1; ++e) {
        int s = sA; sA = sB; sB = sC; sC = sD; sD = colS[e+4];
        sa += tscale[s];
      }
      score[tid] = dinv[tid] * sa + bscp[0];
    }
    __syncthreads();   // B5

    // ---- top-K bitonic sort over NR, desc score / asc id ----
    float kf = -INFINITY; int ki = tid;
    if (tid < NR) {
      kf = score[tid];
      for (int kk = 2; kk <= 64; kk <<= 1)
        for (int j = kk >> 1; j > 0; j >>= 1) {
          float ok = __shfl_xor(kf, j);
          int   oi = __shfl_xor(ki, j);
          BSTEP(ok, oi, kk, j);
        }
    } else if (tid < NR + 8) selM[tid - NR] = 0u;   // clear selection mask (idle threads)

    if constexpr (NR == 256) {
      if (tid < NR) { skey[tid] = kf; sidx[tid] = ki; }
      __syncthreads();
      if (tid < NR) {
        int l = tid ^ 64; float ok = skey[l]; int oi = sidx[l];
        BSTEP(ok, oi, 128, 64);
        for (int j = 32; j > 0; j >>= 1) {
          float sk = __shfl_xor(kf, j); int si = __shfl_xor(ki, j);
          BSTEP(sk, si, 128, j);
        }
      }
      __syncthreads();
      if (tid < NR) { skey[tid] = kf; sidx[tid] = ki; }
      __syncthreads();
      if (tid < NR) {
        int l = tid ^ 128; float ok = skey[l]; int oi = sidx[l];
        BSTEP(ok, oi, 256, 128);
      }
      __syncthreads();
      if (tid < NR) { skey[tid] = kf; sidx[tid] = ki; }
      __syncthreads();
      if (tid < NR) {
        int l = tid ^ 64; float ok = skey[l]; int oi = sidx[l];
        BSTEP(ok, oi, 256, 64);
        for (int j = 32; j > 0; j >>= 1) {
          float sk = __shfl_xor(kf, j); int si = __shfl_xor(ki, j);
          BSTEP(sk, si, 256, j);
        }
      }
    } else if constexpr (NR == 128) {
      if (tid < NR) { skey[tid] = kf; sidx[tid] = ki; }
      __syncthreads();
      if (tid < NR) {
        int l = tid ^ 64; float ok = skey[l]; int oi = sidx[l];
        BSTEP(ok, oi, 128, 64);
        for (int j = 32; j > 0; j >>= 1) {
          float sk = __shfl_xor(kf, j); int si = __shfl_xor(ki, j);
          BSTEP(sk, si, 128, j);
        }
      }
    }
    if constexpr (NR == 64) __syncthreads();       // separate clear from publish
    if constexpr (NR != 64 && NR != 256) __syncthreads();
    if (tid < K) atomicOr(&selM[ki >> 5], 1u << (ki & 31));
    __syncthreads();   // B6: selection published

    // ---- rank (order-preserving compaction) + tanh scale ----
    if (tid < NR) {
      unsigned wsel = selM[tid >> 5];
      bool sel = (wsel >> (tid & 31)) & 1;
      int r = __popc(wsel & ((1u << (tid & 31)) - 1u));
      for (int w = 0; w < (tid >> 5); ++w) r += __popc(selM[w]);
      rank8[tid] = sel ? (unsigned char)r : (unsigned char)0xFF;
      tscale[tid] = sel ? tanhf(score[tid]) : 0.f;
    }
    __syncthreads();   // B7: rank8/tscale ready
    if (tid < NPG) {
      int lv = lut[tid];
      lut[tid] = (lv < NR) ? rank8[lv] : (unsigned char)0xFF;
    }

    // ---- scale + write f32 h' at NEW (compacted) rows ----
    int rk = rank8[v];
    {
      float ts = tscale[v];
      if (rk != 0xFF) {
        #pragma unroll
        for (int j = 0; j < NI; ++j) {
          hv[j].x *= ts; hv[j].y *= ts; hv[j].z *= ts; hv[j].w *= ts;
          *(float4*)&tbufF[rk*FSTR + cb0 + j*4*TPN] = hv[j];
        }
      }
    }
    __syncthreads();   // B8: h' f32 ready (rows 0..K-1)

    // ---- readout over K contiguous rows -> zacc (single pass) ----
    {
      constexpr int RPG = K / 8;
      int f = tid & 127, vg = tid >> 7;
      float mx = -INFINITY, sm = 0.f;
      #pragma unroll
      for (int vr = 0; vr < RPG; ++vr) {
        float val = tbufF[(vg*RPG + vr)*FSTR + f];
        mx = fmaxf(mx, val); sm += val;
      }
      red[vg*HF + f] = mx;
      red2[vg*HF + f] = sm;
      __syncthreads();
      if (tid < HF) {
        float zm = red[tid];
        float zs = red2[tid];
        #pragma unroll
        for (int q2 = 1; q2 < 8; ++q2) {
          zm = fmaxf(zm, red[q2*HF + tid]);
          zs += red2[q2*HF + tid];
        }
        float mn = zs / (float)K;
        if (FIRST) { zacc[tid] = zm; zacc[HF + tid] = mn; }
        else       { zacc[tid] += zm; zacc[HF + tid] += mn; }
      }
      __syncthreads();   // tbufF reads done
    }

    if constexpr (PACK) {
      // ---- pack scaled h' into bf16 pair at NEW rows ----
      if (rk != 0xFF) {
        #pragma unroll
        for (int j = 0; j < NI; ++j) {
          int ci = cb0 + j*4*TPN;
          float4 val = hv[j];
          unsigned rx = rtn16(val.x), ry = rtn16(val.y), rz = rtn16(val.z), rw = rtn16(val.w);
          uint2 ph; ph.x = rx | (ry << 16); ph.y = rz | (rw << 16);
          float lx = val.x - bcf(rx << 16), ly = val.y - bcf(ry << 16);
          float lz = val.z - bcf(rz << 16), lw = val.w - bcf(rw << 16);
          uint2 pl; pl.x = (bcu(lx) >> 16) | (bcu(ly) & 0xFFFF0000u);
          pl.y = (bcu(lz) >> 16) | (bcu(lw) & 0xFFFF0000u);
          *(uint2*)&hp0[rk*PSTR + ci] = ph;
          *(uint2*)&hp1[rk*PSTR + ci] = pl;
        }
      }

      // ---- rebuild CSR in NEW id space (K rows) ----
      if (tid < K) cntA[tid] = 1; else if (tid < NPG) cntA[tid] = 0;
      __syncthreads();
      #pragma unroll
      for (int it = 0; it < 4; ++it) {
        int d2 = lut[dloc[it]], s2 = lut[sloc[it]];
        if (d2 < K && s2 < K) atomicAdd(&cntA[d2], 1);
      }
      __syncthreads();
      WAVE0_SCAN();
      __syncthreads();
      #pragma unroll
      for (int it = 0; it < 4; ++it) {
        int d2 = lut[dloc[it]], s2 = lut[sloc[it]];
        if (d2 < K && s2 < K) {
          int slot = atomicAdd(&curA[d2], 1);
          colS[slot] = (unsigned char)s2;
        }
      }
      if (tid < K) colS[rloc[tid+1] - 1] = (unsigned char)tid;
      // next layer's B0 covers visibility
    }
  };

  run_layer(IC<256>{}, IC<128>{}, BC<true>{},  BC<true>{},
            WtAll,         WtAll + 16384, b1, Ws1, bs1);
  run_layer(IC<128>{}, IC<64>{},  BC<false>{}, BC<true>{},
            WtAll + 32768, WtAll + 49152, b2, Ws2, bs2);
  run_layer(IC<64>{},  IC<32>{},  BC<false>{}, BC<false>{},
            WtAll + 65536, WtAll + 81920, b3, Ws3, bs3);

  __syncthreads();

  // ---- MLP head + log_softmax ----
  {
    int o = tid & 127, kg = tid >> 7;
    float p = 0.f;
    int k0 = kg*32;
    for (int k = k0; k < k0+32; ++k) p += zacc[k]*Wl1[k*HF + o];
    red[kg*HF + o] = p;
    __syncthreads();
    if (tid < HF) {
      float a = bl1[tid];
      #pragma unroll
      for (int q2 = 0; q2 < 8; ++q2) a += red[q2*HF + tid];
      score[tid] = fmaxf(a, 0.f);       // h1
    }
    __syncthreads();
    if (tid < 512) {
      int o2 = tid & 63, kg2 = tid >> 6;
      float p2 = 0.f;
      int k0b = kg2*16;
      for (int k = k0b; k < k0b+16; ++k) p2 += score[k]*Wl2[k*64 + o2];
      red[kg2*64 + o2] = p2;
    }
    __syncthreads();
    if (tid < 64) {
      float a = bl2[tid];
      #pragma unroll
      for (int q2 = 0; q2 < 8; ++q2) a += red[q2*64 + tid];
      tscale[tid] = fmaxf(a, 0.f);      // h2
    }
    __syncthreads();
    if (tid < 10) {
      float a = bl3[tid];
      for (int k = 0; k < 64; ++k) a += tscale[k]*Wl3[k*10 + tid];
      dinv[tid] = fmaxf(a, 0.f);        // logits
    }
    __syncthreads();
    if (tid == 0) {
      float m = dinv[0];
      for (int i = 1; i < 10; ++i) m = fmaxf(m, dinv[i]);
      float s = 0.f;
      for (int i = 0; i < 10; ++i) s += expf(dinv[i] - m);
      red[0] = m; red[1] = logf(s);
    }
    __syncthreads();
    if (tid < 10) out[(size_t)g*10 + tid] = dinv[tid] - red[0] - red[1];
  }
}

extern "C" void kernel_launch(void* const* d_in, const int* in_sizes, int n_in,
                              void* d_out, int out_size, void* d_ws, size_t ws_size,
                              hipStream_t stream) {
  const float* x   = (const float*)d_in[0];
  const int*  srcI = (const int*)d_in[1];
  const int*  dstI = (const int*)d_in[2];
  const float* W1  = (const float*)d_in[3];
  const float* b1  = (const float*)d_in[4];
  const float* W2  = (const float*)d_in[5];
  const float* b2  = (const float*)d_in[6];
  const float* W3  = (const float*)d_in[7];
  const float* b3  = (const float*)d_in[8];
  const float* Ws1 = (const float*)d_in[9];
  const float* bs1 = (const float*)d_in[10];
  const float* Ws2 = (const float*)d_in[11];
  const float* bs2 = (const float*)d_in[12];
  const float* Ws3 = (const float*)d_in[13];
  const float* bs3 = (const float*)d_in[14];
  const float* Wl1 = (const float*)d_in[15];
  const float* bl1 = (const float*)d_in[16];
  const float* Wl2 = (const float*)d_in[17];
  const float* bl2 = (const float*)d_in[18];
  const float* Wl3 = (const float*)d_in[19];
  const float* bl3 = (const float*)d_in[20];
  float* out = (float*)d_out;

  short* WtAll = (short*)d_ws;   // 3 * 2 * 16384 shorts = 192 KB

  prep_wt<<<192, 256, 0, stream>>>(W1, W2, W3, WtAll);
  fused_net<<<NGRAPH, 1024, 0, stream>>>(x, srcI, dstI, WtAll,
                                         b1, Ws1, bs1, b2, Ws2, bs2, b3, Ws3, bs3,
                                         Wl1, bl1, Wl2, bl2, Wl3, bl3, out);
}